// Round 2
// baseline (209.551 us; speedup 1.0000x reference)
//
#include <hip/hip_runtime.h>
#include <hip/hip_bf16.h>
#include <cstdint>

typedef __attribute__((ext_vector_type(8))) __bf16 bf16x8;
typedef __attribute__((ext_vector_type(4))) float f32x4;

typedef __attribute__((address_space(1))) const void g_void;
typedef __attribute__((address_space(3))) void l_void;

__device__ __forceinline__ void gload_lds16(const void* g, void* l) {
  __builtin_amdgcn_global_load_lds((g_void*)(uintptr_t)g,
                                   (l_void*)(uint32_t)(uintptr_t)l, 16, 0, 0);
}

__device__ __forceinline__ ushort f2bf(float f) {
  union { float f; uint32_t u; } v; v.f = f;
  uint32_t r = v.u + 0x7fffu + ((v.u >> 16) & 1u);
  return (ushort)(r >> 16);
}

struct WDesc {
  const float* W[7];
  int nvec[7];
  int vcum[8];
};

// ---------- gamma = mean(|W|) + 1e-8, two-phase deterministic ----------
__global__ void absmean_partial(WDesc wd, float* __restrict__ partials) {
  __shared__ float red[256];
  const int layer = blockIdx.y;
  const float4* W = (const float4*)wd.W[layer];
  const int nv = wd.nvec[layer];
  float s = 0.f;
  for (int i = blockIdx.x * 256 + threadIdx.x; i < nv; i += gridDim.x * 256) {
    float4 w = W[i];
    s += fabsf(w.x) + fabsf(w.y) + fabsf(w.z) + fabsf(w.w);
  }
  red[threadIdx.x] = s;
  __syncthreads();
  for (int o = 128; o > 0; o >>= 1) {
    if (threadIdx.x < o) red[threadIdx.x] += red[threadIdx.x + o];
    __syncthreads();
  }
  if (threadIdx.x == 0) partials[layer * 64 + blockIdx.x] = red[0];
}

__global__ void absmean_final(WDesc wd, const float* __restrict__ partials,
                              float* __restrict__ ig) {
  const int layer = blockIdx.x;
  float v = partials[layer * 64 + threadIdx.x];
  for (int o = 32; o > 0; o >>= 1) v += __shfl_down(v, o, 64);
  if (threadIdx.x == 0) {
    float mean = v / (float)(wd.nvec[layer] * 4);
    ig[layer] = 1.0f / (mean + 1e-8f);
  }
}

// ---------- fused: ternary quantize (all layers) + concat->bf16 ----------
__global__ void prep_kernel(WDesc wd, const float* __restrict__ ig,
                            ushort* __restrict__ qw,
                            const float* __restrict__ z,
                            const float* __restrict__ att,
                            ushort* __restrict__ cat, int qblks) {
  if ((int)blockIdx.x < qblks) {
    const int v = blockIdx.x * 256 + threadIdx.x;
    if (v >= wd.vcum[7]) return;
    int layer = 0;
#pragma unroll
    for (int i = 1; i < 7; ++i) layer += (v >= wd.vcum[i]);
    const int lv = v - wd.vcum[layer];
    const float g = ig[layer];
    float4 w = ((const float4*)wd.W[layer])[lv];
    ushort4 o;
    o.x = f2bf(fmaxf(-1.f, fminf(1.f, rintf(w.x * g))));
    o.y = f2bf(fmaxf(-1.f, fminf(1.f, rintf(w.y * g))));
    o.z = f2bf(fmaxf(-1.f, fminf(1.f, rintf(w.z * g))));
    o.w = f2bf(fmaxf(-1.f, fminf(1.f, rintf(w.w * g))));
    ((ushort4*)qw)[v] = o;
  } else {
    const int tg = (blockIdx.x - qblks) * 256 + threadIdx.x;
    const int row = tg >> 8;
    const int k0 = (tg & 255) * 8;
    const float* src = (k0 < 1024) ? (z + (size_t)row * 1024 + k0)
                                   : (att + (size_t)row * 1024 + (k0 - 1024));
    float4 a = ((const float4*)src)[0];
    float4 b = ((const float4*)src)[1];
    ushort4 o0; o0.x = f2bf(a.x); o0.y = f2bf(a.y); o0.z = f2bf(a.z); o0.w = f2bf(a.w);
    ushort4 o1; o1.x = f2bf(b.x); o1.y = f2bf(b.y); o1.z = f2bf(b.z); o1.w = f2bf(b.w);
    ushort4* dst = (ushort4*)(cat + (size_t)tg * 8);
    dst[0] = o0; dst[1] = o1;
  }
}

// ---------- fast GELU (tanh form, branch-free) ----------
__device__ __forceinline__ float gelu_fast(float x) {
  float x2 = x * x;
  float u = x * fmaf(x2, 0.0356774081f, 0.7978845608f);
  float e = exp2f(u * 2.8853900818f);
  float r = __builtin_amdgcn_rcpf(e + 1.0f);
  return x - x * r;
}

#define SB0() __builtin_amdgcn_sched_barrier(0)
#define BAR() __builtin_amdgcn_s_barrier()
#define LGKM0() asm volatile("s_waitcnt lgkmcnt(0)" ::: "memory")
#define VMW(NN) asm volatile("s_waitcnt vmcnt(%0)" ::"n"(NN) : "memory")

// =====================================================================
// Triple-buffered 1-barrier-per-tile GEMM: BM=256, 8 waves (2M x 4N),
// BK=64, BN in {64,128}. R1: B fragments for ALL FN sub-tiles are held
// in registers (loadB2 once per tile) -> 20 ds_read_b128/tile (was 24).
// Invariant unchanged: all ds_reads of buf X retire before the tile-end
// barrier, so staging into X two tiles later is safe; ONE barrier/tile.
// =====================================================================
template <int BN, bool OUT_F32>
__global__ __launch_bounds__(512, 2)
void gemm_pipe3(const ushort* __restrict__ A, const ushort* __restrict__ Bw,
                const float* __restrict__ bias, void* __restrict__ Cv,
                int M, int N, int K) {
  constexpr int BM = 256;
  constexpr int WN = BN / 4;             // 16 or 32
  constexpr int FM = 8;
  constexpr int FN = WN / 16;            // 1 or 2
  constexpr int HM = 4;
  constexpr int SA = 4;                  // A 64-row chunks
  constexpr int SB = BN / 64;            // B 64-row chunks (1 or 2)
  constexpr int L = SA + SB;
  constexpr int TILE_USH = (BM + BN) * 64;

  __shared__ ushort lds[3 * TILE_USH];

  const int t = threadIdx.x;
  const int lane = t & 63, wid = t >> 6;
  const int wr = wid >> 2, wc = wid & 3;
  const int l15 = lane & 15, lhi = lane >> 4;

  const int gx = gridDim.x;
  const int nwg = gx * gridDim.y;
  int lin = blockIdx.y * gx + blockIdx.x;
  lin = (lin & 7) * (nwg >> 3) + (lin >> 3);  // XCD chunked (nwg % 8 == 0)
  const int bm0 = (lin / gx) * BM, bn0 = (lin % gx) * BN;

  const int NT = K >> 6;

  const int srow = t >> 3;
  const int scol = ((t & 7) ^ ((t >> 3) & 7)) * 8;

  auto stage = [&](int tile, int buf) {
    ushort* tb = &lds[buf * TILE_USH];
    const int kt = tile * 64;
#pragma unroll
    for (int c = 0; c < SA; ++c) {
      const int lr = c * 64 + srow;
      gload_lds16(A + (size_t)(bm0 + lr) * K + kt + scol,
                  &tb[lr * 64 + (t & 7) * 8]);
    }
#pragma unroll
    for (int c = 0; c < SB; ++c) {
      const int lr = c * 64 + srow;
      gload_lds16(Bw + (size_t)(bn0 + lr) * K + kt + scol,
                  &tb[BM * 64 + lr * 64 + (t & 7) * 8]);
    }
  };

  bf16x8 a[HM][2], b2[FN][2];
  f32x4 acc[FM][FN] = {};

  auto loadA = [&](const ushort* tb, int mh) {
#pragma unroll
    for (int mi = 0; mi < HM; ++mi) {
      const int row = wr * 128 + (mh * HM + mi) * 16 + l15;
#pragma unroll
      for (int kh = 0; kh < 2; ++kh)
        a[mi][kh] =
            *(const bf16x8*)&tb[row * 64 + ((kh * 4 + lhi) ^ (l15 & 7)) * 8];
    }
  };
  auto loadB2 = [&](const ushort* tb) {
#pragma unroll
    for (int nf = 0; nf < FN; ++nf) {
      const int row = wc * WN + nf * 16 + l15;
#pragma unroll
      for (int kh = 0; kh < 2; ++kh)
        b2[nf][kh] = *(const bf16x8*)&tb[BM * 64 + row * 64 +
                                         ((kh * 4 + lhi) ^ (l15 & 7)) * 8];
    }
  };

#define MFMA_(MH, NF)                                                        \
  {                                                                          \
    __builtin_amdgcn_s_setprio(1);                                           \
    _Pragma("unroll") for (int kh = 0; kh < 2; ++kh)                         \
    _Pragma("unroll") for (int mi = 0; mi < HM; ++mi)                        \
      acc[(MH) * HM + mi][(NF)] =                                            \
          __builtin_amdgcn_mfma_f32_16x16x32_bf16(                           \
              a[mi][kh], b2[(NF)][kh], acc[(MH) * HM + mi][(NF)],            \
              0, 0, 0);                                                      \
    __builtin_amdgcn_s_setprio(0);                                           \
  }

  // prologue: stage tiles 0,1 into bufs 0,1; wait tile 0; publish.
  stage(0, 0);
  stage(1, 1);
  VMW(L);
  BAR();
  SB0();

  int buf = 0, sbuf = 2;
  for (int tt = 0; tt < NT; ++tt) {
    const bool more = (tt + 2 < NT);
    if (more) stage(tt + 2, sbuf);
    const ushort* tb = &lds[buf * TILE_USH];
    loadA(tb, 0);
    loadB2(tb);
    MFMA_(0, 0);
    if constexpr (FN == 2) { MFMA_(0, 1); }
    loadA(tb, 1);
    MFMA_(1, 0);
    if constexpr (FN == 2) { MFMA_(1, 1); }
    SB0();
    if (more) { VMW(L); } else { VMW(0); }
    BAR();
    SB0();
    buf = (buf == 2) ? 0 : buf + 1;
    sbuf = (sbuf == 2) ? 0 : sbuf + 1;
  }
#undef MFMA_

#pragma unroll
  for (int n = 0; n < FN; ++n) {
    const int col = bn0 + wc * WN + n * 16 + l15;
    const float bv = bias[col];
#pragma unroll
    for (int m = 0; m < FM; ++m) {
      const int row0 = bm0 + wr * 128 + m * 16 + lhi * 4;
#pragma unroll
      for (int j = 0; j < 4; ++j) {
        float v = acc[m][n][j] + bv;
        float gv = gelu_fast(v);
        if (OUT_F32)
          ((float*)Cv)[(size_t)(row0 + j) * N + col] = gv;
        else
          ((ushort*)Cv)[(size_t)(row0 + j) * N + col] = f2bf(gv);
      }
    }
  }
}

// =====================================================================
// 2-barrier-per-tile GEMM for BN=256 (R7-verified), static 2-tile unroll.
// R1: B fragments held in b2[2][HN][2] -> 24 ds_read_b128/tile (was 32).
// MFMA_(1,0) after the mid-tile barrier is register-only (overlaps the
// stage() of tile TT+2), same invariant as before.
// =====================================================================
template <int BN, bool OUT_F32>
__global__ __launch_bounds__(512, 2)
void gemm_half(const ushort* __restrict__ A, const ushort* __restrict__ Bw,
               const float* __restrict__ bias, void* __restrict__ Cv,
               int M, int N, int K) {
  constexpr int BM = 256;
  constexpr int WN = BN / 4;
  constexpr int FM = 8;
  constexpr int FN = WN / 16;
  constexpr int HM = 4;
  constexpr int HN = FN / 2;
  constexpr int SA = 4;
  constexpr int SB = BN / 64;
  constexpr int L = SA + SB;
  constexpr int TILE_USH = (BM + BN) * 64;

  __shared__ ushort lds[2 * TILE_USH];

  const int t = threadIdx.x;
  const int lane = t & 63, wid = t >> 6;
  const int wr = wid >> 2, wc = wid & 3;
  const int l15 = lane & 15, lhi = lane >> 4;

  const int gx = gridDim.x;
  const int nwg = gx * gridDim.y;
  int lin = blockIdx.y * gx + blockIdx.x;
  lin = (lin & 7) * (nwg >> 3) + (lin >> 3);
  const int bm0 = (lin / gx) * BM, bn0 = (lin % gx) * BN;

  const int NT = K >> 6;

  const int srow = t >> 3;
  const int scol = ((t & 7) ^ ((t >> 3) & 7)) * 8;

  auto stage = [&](int tile, int buf) {
    ushort* tb = &lds[buf * TILE_USH];
    const int kt = tile * 64;
#pragma unroll
    for (int c = 0; c < SA; ++c) {
      const int lr = c * 64 + srow;
      gload_lds16(A + (size_t)(bm0 + lr) * K + kt + scol,
                  &tb[lr * 64 + (t & 7) * 8]);
    }
#pragma unroll
    for (int c = 0; c < SB; ++c) {
      const int lr = c * 64 + srow;
      gload_lds16(Bw + (size_t)(bn0 + lr) * K + kt + scol,
                  &tb[BM * 64 + lr * 64 + (t & 7) * 8]);
    }
  };

  bf16x8 a[HM][2], b2[2][HN][2];
  f32x4 acc[FM][FN] = {};

  auto loadA = [&](const ushort* tb, int mh) {
#pragma unroll
    for (int mi = 0; mi < HM; ++mi) {
      const int row = wr * 128 + (mh * HM + mi) * 16 + l15;
#pragma unroll
      for (int kh = 0; kh < 2; ++kh)
        a[mi][kh] =
            *(const bf16x8*)&tb[row * 64 + ((kh * 4 + lhi) ^ (l15 & 7)) * 8];
    }
  };
  auto loadB = [&](const ushort* tb, int nh) {
#pragma unroll
    for (int ni = 0; ni < HN; ++ni) {
      const int row = wc * WN + (nh * HN + ni) * 16 + l15;
#pragma unroll
      for (int kh = 0; kh < 2; ++kh)
        b2[nh][ni][kh] = *(const bf16x8*)&tb[BM * 64 + row * 64 +
                                             ((kh * 4 + lhi) ^ (l15 & 7)) * 8];
    }
  };

#define MFMA_(MH, NH)                                                        \
  {                                                                          \
    __builtin_amdgcn_s_setprio(1);                                           \
    _Pragma("unroll") for (int kh = 0; kh < 2; ++kh)                         \
    _Pragma("unroll") for (int mi = 0; mi < HM; ++mi)                        \
    _Pragma("unroll") for (int ni = 0; ni < HN; ++ni)                        \
      acc[(MH) * HM + mi][(NH) * HN + ni] =                                  \
          __builtin_amdgcn_mfma_f32_16x16x32_bf16(                           \
              a[mi][kh], b2[(NH)][ni][kh],                                   \
              acc[(MH) * HM + mi][(NH) * HN + ni], 0, 0, 0);                 \
    __builtin_amdgcn_s_setprio(0);                                           \
  }

#define TILE_(P, TT)                                                         \
  {                                                                          \
    const bool more = (TT) + 2 < NT;                                         \
    const ushort* tb = &lds[(P) * TILE_USH];                                 \
    loadA(tb, 0); loadB(tb, 0); loadB(tb, 1);                                \
    MFMA_(0, 0);                                                             \
    MFMA_(0, 1);                                                             \
    loadA(tb, 1);                                                            \
    MFMA_(1, 1);                                                             \
    LGKM0();                                                                 \
    BAR();                                                                   \
    SB0();                                                                   \
    if (more) stage((TT) + 2, P);                                            \
    MFMA_(1, 0);                                                             \
    SB0();                                                                   \
    if (more) { VMW(L); } else { VMW(0); }                                   \
    BAR();                                                                   \
    SB0();                                                                   \
  }

  stage(0, 0);
  stage(1, 1);
  VMW(L);
  BAR();
  SB0();

  for (int it = 0; it < (NT >> 1); ++it) {
    TILE_(0, 2 * it);
    TILE_(1, 2 * it + 1);
  }
#undef TILE_
#undef MFMA_

#pragma unroll
  for (int n = 0; n < FN; ++n) {
    const int col = bn0 + wc * WN + n * 16 + l15;
    const float bv = bias[col];
#pragma unroll
    for (int m = 0; m < FM; ++m) {
      const int row0 = bm0 + wr * 128 + m * 16 + lhi * 4;
#pragma unroll
      for (int j = 0; j < 4; ++j) {
        float v = acc[m][n][j] + bv;
        float gv = gelu_fast(v);
        if (OUT_F32)
          ((float*)Cv)[(size_t)(row0 + j) * N + col] = gv;
        else
          ((ushort*)Cv)[(size_t)(row0 + j) * N + col] = f2bf(gv);
      }
    }
  }
}

// ---------- 2-phase GEMM for small layers (proven R2 structure) ----------
template <int BM, int BN, bool OUT_F32>
__global__ __launch_bounds__(256, 4)
void gemm_bt_bias_gelu(const ushort* __restrict__ A, const ushort* __restrict__ Bw,
                       const float* __restrict__ bias, void* __restrict__ Cv,
                       int M, int N, int K) {
  constexpr int WTM = BM / 32;
  constexpr int WTN = BN / 32;
  __shared__ ushort As[BM * 64];
  __shared__ ushort Bs[BN * 64];
  const int t = threadIdx.x;
  const int lane = t & 63, wid = t >> 6;
  const int wr = wid >> 1, wc = wid & 1;
  const int l15 = lane & 15, lhi = lane >> 4;

  const int gx = gridDim.x;
  const int nwg = gx * gridDim.y;
  int lin = blockIdx.y * gx + blockIdx.x;
  if ((nwg & 7) == 0) lin = (lin & 7) * (nwg >> 3) + (lin >> 3);
  const int bm0 = (lin / gx) * BM, bn0 = (lin % gx) * BN;

  const ushort* Abase = A + (size_t)bm0 * K;
  const ushort* Bbase = Bw + (size_t)bn0 * K;

  f32x4 acc[WTM][WTN] = {};

  for (int kt = 0; kt < K; kt += 64) {
#pragma unroll
    for (int i = 0; i < BM / 32; ++i) {
      int c = i * 256 + t;
      int r = c >> 3, c8 = c & 7;
      gload_lds16(Abase + (size_t)r * K + kt + c8 * 8, &As[c * 8]);
    }
#pragma unroll
    for (int i = 0; i < BN / 32; ++i) {
      int c = i * 256 + t;
      int r = c >> 3, c8 = c & 7;
      gload_lds16(Bbase + (size_t)r * K + kt + c8 * 8, &Bs[c * 8]);
    }
    asm volatile("s_waitcnt vmcnt(0)" ::: "memory");
    __syncthreads();
#pragma unroll
    for (int kk = 0; kk < 64; kk += 32) {
      bf16x8 af[WTM], bfr[WTN];
#pragma unroll
      for (int m = 0; m < WTM; ++m)
        af[m] = *(const bf16x8*)&As[(wr * (BM / 2) + m * 16 + l15) * 64 + kk + lhi * 8];
#pragma unroll
      for (int n = 0; n < WTN; ++n)
        bfr[n] = *(const bf16x8*)&Bs[(wc * (BN / 2) + n * 16 + l15) * 64 + kk + lhi * 8];
#pragma unroll
      for (int m = 0; m < WTM; ++m)
#pragma unroll
        for (int n = 0; n < WTN; ++n)
          acc[m][n] = __builtin_amdgcn_mfma_f32_16x16x32_bf16(af[m], bfr[n], acc[m][n], 0, 0, 0);
    }
    __syncthreads();
  }

#pragma unroll
  for (int n = 0; n < WTN; ++n) {
    const int col = bn0 + wc * (BN / 2) + n * 16 + l15;
    const float bv = bias[col];
#pragma unroll
    for (int m = 0; m < WTM; ++m) {
      const int row0 = bm0 + wr * (BM / 2) + m * 16 + lhi * 4;
#pragma unroll
      for (int j = 0; j < 4; ++j) {
        float v = acc[m][n][j] + bv;
        float gv = gelu_fast(v);
        if (OUT_F32)
          ((float*)Cv)[(size_t)(row0 + j) * N + col] = gv;
        else
          ((ushort*)Cv)[(size_t)(row0 + j) * N + col] = f2bf(gv);
      }
    }
  }
}

extern "C" void kernel_launch(void* const* d_in, const int* in_sizes, int n_in,
                              void* d_out, int out_size, void* d_ws, size_t ws_size,
                              hipStream_t stream) {
  const float* z   = (const float*)d_in[0];
  const float* att = (const float*)d_in[1];
  const float* Wptr[7] = {(const float*)d_in[2],  (const float*)d_in[4],
                          (const float*)d_in[6],  (const float*)d_in[8],
                          (const float*)d_in[10], (const float*)d_in[12],
                          (const float*)d_in[14]};
  const float* bptr[7] = {(const float*)d_in[3],  (const float*)d_in[5],
                          (const float*)d_in[7],  (const float*)d_in[9],
                          (const float*)d_in[11], (const float*)d_in[13],
                          (const float*)d_in[15]};
  const int Ns[7] = {1024, 512, 256, 256, 512, 1024, 2048};
  const int Ks[7] = {2048, 1024, 512, 256, 256, 512, 1024};
  const int M = 8192;

  char* ws = (char*)d_ws;
  ushort* bufA = (ushort*)ws;
  ushort* bufB = (ushort*)(ws + 33554432);
  ushort* qw   = (ushort*)(ws + 33554432 + 16777216);
  float* partials = (float*)(ws + 33554432 + 16777216 + 11141120);
  float* ig = partials + 7 * 64;

  WDesc wd;
  int cum = 0;
  size_t qoff[7]; size_t qc = 0;
  for (int l = 0; l < 7; ++l) {
    wd.W[l] = Wptr[l];
    int nv = Ns[l] * Ks[l] / 4;
    wd.nvec[l] = nv;
    wd.vcum[l] = cum;
    cum += nv;
    qoff[l] = qc;
    qc += (size_t)Ns[l] * Ks[l];
  }
  wd.vcum[7] = cum;

  const int qblks = (cum + 255) / 256;
  absmean_partial<<<dim3(64, 7), 256, 0, stream>>>(wd, partials);
  absmean_final<<<7, 64, 0, stream>>>(wd, partials, ig);
  prep_kernel<<<qblks + 8192, 256, 0, stream>>>(wd, ig, qw, z, att, bufA, qblks);

  ushort* inb = bufA; ushort* outb = bufB;
  // L0: 8192x1024, K=2048 -> pipe3 <BN=128>, grid (8,32)=256
  gemm_pipe3<128, false><<<dim3(Ns[0] / 128, M / 256), dim3(512), 0, stream>>>(
      inb, qw + qoff[0], bptr[0], outb, M, Ns[0], Ks[0]);
  { ushort* tmp = inb; inb = outb; outb = tmp; }
  // L1: 8192x512, K=1024 -> pipe3 <BN=64>, grid (8,32)=256
  gemm_pipe3<64, false><<<dim3(Ns[1] / 64, M / 256), dim3(512), 0, stream>>>(
      inb, qw + qoff[1], bptr[1], outb, M, Ns[1], Ks[1]);
  { ushort* tmp = inb; inb = outb; outb = tmp; }
  // L2: 8192x256, K=512 -> 2-phase <64,64>
  gemm_bt_bias_gelu<64, 64, false><<<dim3(Ns[2] / 64, M / 64), 256, 0, stream>>>(
      inb, qw + qoff[2], bptr[2], outb, M, Ns[2], Ks[2]);
  { ushort* tmp = inb; inb = outb; outb = tmp; }
  // L3: 8192x256, K=256 -> 2-phase <64,64>
  gemm_bt_bias_gelu<64, 64, false><<<dim3(Ns[3] / 64, M / 64), 256, 0, stream>>>(
      inb, qw + qoff[3], bptr[3], outb, M, Ns[3], Ks[3]);
  { ushort* tmp = inb; inb = outb; outb = tmp; }
  // L4: 8192x512, K=256 -> pipe3 <BN=64>, grid (8,32)=256
  gemm_pipe3<64, false><<<dim3(Ns[4] / 64, M / 256), dim3(512), 0, stream>>>(
      inb, qw + qoff[4], bptr[4], outb, M, Ns[4], Ks[4]);
  { ushort* tmp = inb; inb = outb; outb = tmp; }
  // L5: 8192x1024, K=512 -> pipe3 <BN=128>, grid (8,32)
  gemm_pipe3<128, false><<<dim3(Ns[5] / 128, M / 256), dim3(512), 0, stream>>>(
      inb, qw + qoff[5], bptr[5], outb, M, Ns[5], Ks[5]);
  { ushort* tmp = inb; inb = outb; outb = tmp; }
  // L6: 8192x2048, K=1024 -> gemm_half <BN=256> (R0 showed pipe3<128> is
  // WORSE here: FETCH 25.8->41.1 MB from halved A-reuse, dur 50->54).
  gemm_half<256, true><<<dim3(Ns[6] / 256, M / 256), dim3(512), 0, stream>>>(
      inb, qw + qoff[6], bptr[6], d_out, M, Ns[6], Ks[6]);
}

// Round 3
// 186.566 us; speedup vs baseline: 1.1232x; 1.1232x over previous
//
#include <hip/hip_runtime.h>
#include <hip/hip_bf16.h>
#include <cstdint>

typedef __attribute__((ext_vector_type(8))) __bf16 bf16x8;
typedef __attribute__((ext_vector_type(4))) float f32x4;

typedef __attribute__((address_space(1))) const void g_void;
typedef __attribute__((address_space(3))) void l_void;

__device__ __forceinline__ void gload_lds16(const void* g, void* l) {
  __builtin_amdgcn_global_load_lds((g_void*)(uintptr_t)g,
                                   (l_void*)(uint32_t)(uintptr_t)l, 16, 0, 0);
}

__device__ __forceinline__ ushort f2bf(float f) {
  union { float f; uint32_t u; } v; v.f = f;
  uint32_t r = v.u + 0x7fffu + ((v.u >> 16) & 1u);
  return (ushort)(r >> 16);
}

struct WDesc {
  const float* W[7];
  int nvec[7];
  int vcum[8];
};

// ---------- gamma = mean(|W|) + 1e-8, two-phase deterministic ----------
__global__ void absmean_partial(WDesc wd, float* __restrict__ partials) {
  __shared__ float red[256];
  const int layer = blockIdx.y;
  const float4* W = (const float4*)wd.W[layer];
  const int nv = wd.nvec[layer];
  float s = 0.f;
  for (int i = blockIdx.x * 256 + threadIdx.x; i < nv; i += gridDim.x * 256) {
    float4 w = W[i];
    s += fabsf(w.x) + fabsf(w.y) + fabsf(w.z) + fabsf(w.w);
  }
  red[threadIdx.x] = s;
  __syncthreads();
  for (int o = 128; o > 0; o >>= 1) {
    if (threadIdx.x < o) red[threadIdx.x] += red[threadIdx.x + o];
    __syncthreads();
  }
  if (threadIdx.x == 0) partials[layer * 64 + blockIdx.x] = red[0];
}

__global__ void absmean_final(WDesc wd, const float* __restrict__ partials,
                              float* __restrict__ ig) {
  const int layer = blockIdx.x;
  float v = partials[layer * 64 + threadIdx.x];
  for (int o = 32; o > 0; o >>= 1) v += __shfl_down(v, o, 64);
  if (threadIdx.x == 0) {
    float mean = v / (float)(wd.nvec[layer] * 4);
    ig[layer] = 1.0f / (mean + 1e-8f);
  }
}

// ---------- fused: ternary quantize (all layers) + concat->bf16 ----------
__global__ void prep_kernel(WDesc wd, const float* __restrict__ ig,
                            ushort* __restrict__ qw,
                            const float* __restrict__ z,
                            const float* __restrict__ att,
                            ushort* __restrict__ cat, int qblks) {
  if ((int)blockIdx.x < qblks) {
    const int v = blockIdx.x * 256 + threadIdx.x;
    if (v >= wd.vcum[7]) return;
    int layer = 0;
#pragma unroll
    for (int i = 1; i < 7; ++i) layer += (v >= wd.vcum[i]);
    const int lv = v - wd.vcum[layer];
    const float g = ig[layer];
    float4 w = ((const float4*)wd.W[layer])[lv];
    ushort4 o;
    o.x = f2bf(fmaxf(-1.f, fminf(1.f, rintf(w.x * g))));
    o.y = f2bf(fmaxf(-1.f, fminf(1.f, rintf(w.y * g))));
    o.z = f2bf(fmaxf(-1.f, fminf(1.f, rintf(w.z * g))));
    o.w = f2bf(fmaxf(-1.f, fminf(1.f, rintf(w.w * g))));
    ((ushort4*)qw)[v] = o;
  } else {
    const int tg = (blockIdx.x - qblks) * 256 + threadIdx.x;
    const int row = tg >> 8;
    const int k0 = (tg & 255) * 8;
    const float* src = (k0 < 1024) ? (z + (size_t)row * 1024 + k0)
                                   : (att + (size_t)row * 1024 + (k0 - 1024));
    float4 a = ((const float4*)src)[0];
    float4 b = ((const float4*)src)[1];
    ushort4 o0; o0.x = f2bf(a.x); o0.y = f2bf(a.y); o0.z = f2bf(a.z); o0.w = f2bf(a.w);
    ushort4 o1; o1.x = f2bf(b.x); o1.y = f2bf(b.y); o1.z = f2bf(b.z); o1.w = f2bf(b.w);
    ushort4* dst = (ushort4*)(cat + (size_t)tg * 8);
    dst[0] = o0; dst[1] = o1;
  }
}

// ---------- fast GELU (tanh form, branch-free) ----------
__device__ __forceinline__ float gelu_fast(float x) {
  float x2 = x * x;
  float u = x * fmaf(x2, 0.0356774081f, 0.7978845608f);
  float e = exp2f(u * 2.8853900818f);
  float r = __builtin_amdgcn_rcpf(e + 1.0f);
  return x - x * r;
}

#define SB0() __builtin_amdgcn_sched_barrier(0)
#define BAR() __builtin_amdgcn_s_barrier()
#define LGKM0() asm volatile("s_waitcnt lgkmcnt(0)" ::: "memory")
#define VMW(NN) asm volatile("s_waitcnt vmcnt(%0)" ::"n"(NN) : "memory")

// =====================================================================
// Triple-buffered 1-barrier-per-tile GEMM: BM=256, 8 waves (2M x 4N),
// BK=64, BN in {64,128}. R0-exact schedule (R1's loadB2 variant was
// neutral; R2's register-holding in gemm_half regressed hard -> this
// schedule is compiler-pipeline-fragile, keep verbatim).
// =====================================================================
template <int BN, bool OUT_F32>
__global__ __launch_bounds__(512, 2)
void gemm_pipe3(const ushort* __restrict__ A, const ushort* __restrict__ Bw,
                const float* __restrict__ bias, void* __restrict__ Cv,
                int M, int N, int K) {
  constexpr int BM = 256;
  constexpr int WN = BN / 4;             // 16 or 32
  constexpr int FM = 8;
  constexpr int FN = WN / 16;            // 1 or 2
  constexpr int HM = 4;
  constexpr int HN = 1;
  constexpr int SA = 4;                  // A 64-row chunks
  constexpr int SB = BN / 64;            // B 64-row chunks (1 or 2)
  constexpr int L = SA + SB;
  constexpr int TILE_USH = (BM + BN) * 64;

  __shared__ ushort lds[3 * TILE_USH];

  const int t = threadIdx.x;
  const int lane = t & 63, wid = t >> 6;
  const int wr = wid >> 2, wc = wid & 3;
  const int l15 = lane & 15, lhi = lane >> 4;

  const int gx = gridDim.x;
  const int nwg = gx * gridDim.y;
  int lin = blockIdx.y * gx + blockIdx.x;
  lin = (lin & 7) * (nwg >> 3) + (lin >> 3);  // XCD chunked (nwg % 8 == 0)
  const int bm0 = (lin / gx) * BM, bn0 = (lin % gx) * BN;

  const int NT = K >> 6;

  const int srow = t >> 3;
  const int scol = ((t & 7) ^ ((t >> 3) & 7)) * 8;

  auto stage = [&](int tile, int buf) {
    ushort* tb = &lds[buf * TILE_USH];
    const int kt = tile * 64;
#pragma unroll
    for (int c = 0; c < SA; ++c) {
      const int lr = c * 64 + srow;
      gload_lds16(A + (size_t)(bm0 + lr) * K + kt + scol,
                  &tb[lr * 64 + (t & 7) * 8]);
    }
#pragma unroll
    for (int c = 0; c < SB; ++c) {
      const int lr = c * 64 + srow;
      gload_lds16(Bw + (size_t)(bn0 + lr) * K + kt + scol,
                  &tb[BM * 64 + lr * 64 + (t & 7) * 8]);
    }
  };

  bf16x8 a[HM][2], b[HN][2];
  f32x4 acc[FM][FN] = {};

  auto loadA = [&](const ushort* tb, int mh) {
#pragma unroll
    for (int mi = 0; mi < HM; ++mi) {
      const int row = wr * 128 + (mh * HM + mi) * 16 + l15;
#pragma unroll
      for (int kh = 0; kh < 2; ++kh)
        a[mi][kh] =
            *(const bf16x8*)&tb[row * 64 + ((kh * 4 + lhi) ^ (l15 & 7)) * 8];
    }
  };
  auto loadB = [&](const ushort* tb, int nh) {
#pragma unroll
    for (int ni = 0; ni < HN; ++ni) {
      const int row = wc * WN + (nh * HN + ni) * 16 + l15;
#pragma unroll
      for (int kh = 0; kh < 2; ++kh)
        b[ni][kh] = *(const bf16x8*)&tb[BM * 64 + row * 64 +
                                        ((kh * 4 + lhi) ^ (l15 & 7)) * 8];
    }
  };

#define MFMA_(MH, NH)                                                        \
  {                                                                          \
    __builtin_amdgcn_s_setprio(1);                                           \
    _Pragma("unroll") for (int kh = 0; kh < 2; ++kh)                         \
    _Pragma("unroll") for (int mi = 0; mi < HM; ++mi)                        \
    _Pragma("unroll") for (int ni = 0; ni < HN; ++ni)                        \
      acc[(MH) * HM + mi][(NH) * HN + ni] =                                  \
          __builtin_amdgcn_mfma_f32_16x16x32_bf16(                           \
              a[mi][kh], b[ni][kh], acc[(MH) * HM + mi][(NH) * HN + ni],     \
              0, 0, 0);                                                      \
    __builtin_amdgcn_s_setprio(0);                                           \
  }

  // prologue: stage tiles 0,1 into bufs 0,1; wait tile 0; publish.
  stage(0, 0);
  stage(1, 1);
  VMW(L);
  BAR();
  SB0();

  int buf = 0, sbuf = 2;
  for (int tt = 0; tt < NT; ++tt) {
    const bool more = (tt + 2 < NT);
    if (more) stage(tt + 2, sbuf);
    const ushort* tb = &lds[buf * TILE_USH];
    if constexpr (FN == 2) {
      loadA(tb, 0); loadB(tb, 0);
      MFMA_(0, 0);
      loadB(tb, 1);
      MFMA_(0, 1);
      loadA(tb, 1);
      MFMA_(1, 1);
      loadB(tb, 0);
      MFMA_(1, 0);
    } else {
      loadA(tb, 0); loadB(tb, 0);
      MFMA_(0, 0);
      loadA(tb, 1);
      MFMA_(1, 0);
    }
    SB0();
    if (more) { VMW(L); } else { VMW(0); }
    BAR();
    SB0();
    buf = (buf == 2) ? 0 : buf + 1;
    sbuf = (sbuf == 2) ? 0 : sbuf + 1;
  }
#undef MFMA_

#pragma unroll
  for (int n = 0; n < FN; ++n) {
    const int col = bn0 + wc * WN + n * 16 + l15;
    const float bv = bias[col];
#pragma unroll
    for (int m = 0; m < FM; ++m) {
      const int row0 = bm0 + wr * 128 + m * 16 + lhi * 4;
#pragma unroll
      for (int j = 0; j < 4; ++j) {
        float v = acc[m][n][j] + bv;
        float gv = gelu_fast(v);
        if (OUT_F32)
          ((float*)Cv)[(size_t)(row0 + j) * N + col] = gv;
        else
          ((ushort*)Cv)[(size_t)(row0 + j) * N + col] = f2bf(gv);
      }
    }
  }
}

// =====================================================================
// 2-barrier-per-tile GEMM for BN=256, static 2-tile unroll (R0-exact;
// R2's register-held-B variant regressed 51->77 us, do not touch).
// Kept as fallback if the 128^2 2-phase loses on L6.
// =====================================================================
template <int BN, bool OUT_F32>
__global__ __launch_bounds__(512, 2)
void gemm_half(const ushort* __restrict__ A, const ushort* __restrict__ Bw,
               const float* __restrict__ bias, void* __restrict__ Cv,
               int M, int N, int K) {
  constexpr int BM = 256;
  constexpr int WN = BN / 4;
  constexpr int FM = 8;
  constexpr int FN = WN / 16;
  constexpr int HM = 4;
  constexpr int HN = FN / 2;
  constexpr int SA = 4;
  constexpr int SB = BN / 64;
  constexpr int L = SA + SB;
  constexpr int TILE_USH = (BM + BN) * 64;

  __shared__ ushort lds[2 * TILE_USH];

  const int t = threadIdx.x;
  const int lane = t & 63, wid = t >> 6;
  const int wr = wid >> 2, wc = wid & 3;
  const int l15 = lane & 15, lhi = lane >> 4;

  const int gx = gridDim.x;
  const int nwg = gx * gridDim.y;
  int lin = blockIdx.y * gx + blockIdx.x;
  lin = (lin & 7) * (nwg >> 3) + (lin >> 3);
  const int bm0 = (lin / gx) * BM, bn0 = (lin % gx) * BN;

  const int NT = K >> 6;

  const int srow = t >> 3;
  const int scol = ((t & 7) ^ ((t >> 3) & 7)) * 8;

  auto stage = [&](int tile, int buf) {
    ushort* tb = &lds[buf * TILE_USH];
    const int kt = tile * 64;
#pragma unroll
    for (int c = 0; c < SA; ++c) {
      const int lr = c * 64 + srow;
      gload_lds16(A + (size_t)(bm0 + lr) * K + kt + scol,
                  &tb[lr * 64 + (t & 7) * 8]);
    }
#pragma unroll
    for (int c = 0; c < SB; ++c) {
      const int lr = c * 64 + srow;
      gload_lds16(Bw + (size_t)(bn0 + lr) * K + kt + scol,
                  &tb[BM * 64 + lr * 64 + (t & 7) * 8]);
    }
  };

  bf16x8 a[HM][2], b[HN][2];
  f32x4 acc[FM][FN] = {};

  auto loadA = [&](const ushort* tb, int mh) {
#pragma unroll
    for (int mi = 0; mi < HM; ++mi) {
      const int row = wr * 128 + (mh * HM + mi) * 16 + l15;
#pragma unroll
      for (int kh = 0; kh < 2; ++kh)
        a[mi][kh] =
            *(const bf16x8*)&tb[row * 64 + ((kh * 4 + lhi) ^ (l15 & 7)) * 8];
    }
  };
  auto loadB = [&](const ushort* tb, int nh) {
#pragma unroll
    for (int ni = 0; ni < HN; ++ni) {
      const int row = wc * WN + (nh * HN + ni) * 16 + l15;
#pragma unroll
      for (int kh = 0; kh < 2; ++kh)
        b[ni][kh] = *(const bf16x8*)&tb[BM * 64 + row * 64 +
                                        ((kh * 4 + lhi) ^ (l15 & 7)) * 8];
    }
  };

#define MFMA_(MH, NH)                                                        \
  {                                                                          \
    __builtin_amdgcn_s_setprio(1);                                           \
    _Pragma("unroll") for (int kh = 0; kh < 2; ++kh)                         \
    _Pragma("unroll") for (int mi = 0; mi < HM; ++mi)                        \
    _Pragma("unroll") for (int ni = 0; ni < HN; ++ni)                        \
      acc[(MH) * HM + mi][(NH) * HN + ni] =                                  \
          __builtin_amdgcn_mfma_f32_16x16x32_bf16(                           \
              a[mi][kh], b[ni][kh], acc[(MH) * HM + mi][(NH) * HN + ni],     \
              0, 0, 0);                                                      \
    __builtin_amdgcn_s_setprio(0);                                           \
  }

#define TILE_(P, TT)                                                         \
  {                                                                          \
    const bool more = (TT) + 2 < NT;                                         \
    const ushort* tb = &lds[(P) * TILE_USH];                                 \
    loadA(tb, 0); loadB(tb, 0);                                              \
    MFMA_(0, 0);                                                             \
    loadB(tb, 1);                                                            \
    MFMA_(0, 1);                                                             \
    loadA(tb, 1);                                                            \
    MFMA_(1, 1);                                                             \
    loadB(tb, 0);                                                            \
    LGKM0();                                                                 \
    BAR();                                                                   \
    SB0();                                                                   \
    if (more) stage((TT) + 2, P);                                            \
    MFMA_(1, 0);                                                             \
    SB0();                                                                   \
    if (more) { VMW(L); } else { VMW(0); }                                   \
    BAR();                                                                   \
    SB0();                                                                   \
  }

  stage(0, 0);
  stage(1, 1);
  VMW(L);
  BAR();
  SB0();

  for (int it = 0; it < (NT >> 1); ++it) {
    TILE_(0, 2 * it);
    TILE_(1, 2 * it + 1);
  }
#undef TILE_
#undef MFMA_

#pragma unroll
  for (int n = 0; n < FN; ++n) {
    const int col = bn0 + wc * WN + n * 16 + l15;
    const float bv = bias[col];
#pragma unroll
    for (int m = 0; m < FM; ++m) {
      const int row0 = bm0 + wr * 128 + m * 16 + lhi * 4;
#pragma unroll
      for (int j = 0; j < 4; ++j) {
        float v = acc[m][n][j] + bv;
        float gv = gelu_fast(v);
        if (OUT_F32)
          ((float*)Cv)[(size_t)(row0 + j) * N + col] = gv;
        else
          ((ushort*)Cv)[(size_t)(row0 + j) * N + col] = f2bf(gv);
      }
    }
  }
}

// ---------- 2-phase GEMM (proven structure; m97-class at 128x128) ----------
// 4 waves, single-buffer LDS, vmcnt(0)+syncthreads per K-tile. At
// <128,128>: 32 KB LDS -> ~4 blocks/CU; cross-block wave overlap (m114)
// hides the drain that 1-block/CU structures cannot.
template <int BM, int BN, bool OUT_F32>
__global__ __launch_bounds__(256, 4)
void gemm_bt_bias_gelu(const ushort* __restrict__ A, const ushort* __restrict__ Bw,
                       const float* __restrict__ bias, void* __restrict__ Cv,
                       int M, int N, int K) {
  constexpr int WTM = BM / 32;
  constexpr int WTN = BN / 32;
  __shared__ ushort As[BM * 64];
  __shared__ ushort Bs[BN * 64];
  const int t = threadIdx.x;
  const int lane = t & 63, wid = t >> 6;
  const int wr = wid >> 1, wc = wid & 1;
  const int l15 = lane & 15, lhi = lane >> 4;

  const int gx = gridDim.x;
  const int nwg = gx * gridDim.y;
  int lin = blockIdx.y * gx + blockIdx.x;
  if ((nwg & 7) == 0) lin = (lin & 7) * (nwg >> 3) + (lin >> 3);
  const int bm0 = (lin / gx) * BM, bn0 = (lin % gx) * BN;

  const ushort* Abase = A + (size_t)bm0 * K;
  const ushort* Bbase = Bw + (size_t)bn0 * K;

  f32x4 acc[WTM][WTN] = {};

  for (int kt = 0; kt < K; kt += 64) {
#pragma unroll
    for (int i = 0; i < BM / 32; ++i) {
      int c = i * 256 + t;
      int r = c >> 3, c8 = c & 7;
      gload_lds16(Abase + (size_t)r * K + kt + c8 * 8, &As[c * 8]);
    }
#pragma unroll
    for (int i = 0; i < BN / 32; ++i) {
      int c = i * 256 + t;
      int r = c >> 3, c8 = c & 7;
      gload_lds16(Bbase + (size_t)r * K + kt + c8 * 8, &Bs[c * 8]);
    }
    asm volatile("s_waitcnt vmcnt(0)" ::: "memory");
    __syncthreads();
#pragma unroll
    for (int kk = 0; kk < 64; kk += 32) {
      bf16x8 af[WTM], bfr[WTN];
#pragma unroll
      for (int m = 0; m < WTM; ++m)
        af[m] = *(const bf16x8*)&As[(wr * (BM / 2) + m * 16 + l15) * 64 + kk + lhi * 8];
#pragma unroll
      for (int n = 0; n < WTN; ++n)
        bfr[n] = *(const bf16x8*)&Bs[(wc * (BN / 2) + n * 16 + l15) * 64 + kk + lhi * 8];
#pragma unroll
      for (int m = 0; m < WTM; ++m)
#pragma unroll
        for (int n = 0; n < WTN; ++n)
          acc[m][n] = __builtin_amdgcn_mfma_f32_16x16x32_bf16(af[m], bfr[n], acc[m][n], 0, 0, 0);
    }
    __syncthreads();
  }

#pragma unroll
  for (int n = 0; n < WTN; ++n) {
    const int col = bn0 + wc * (BN / 2) + n * 16 + l15;
    const float bv = bias[col];
#pragma unroll
    for (int m = 0; m < WTM; ++m) {
      const int row0 = bm0 + wr * (BM / 2) + m * 16 + lhi * 4;
#pragma unroll
      for (int j = 0; j < 4; ++j) {
        float v = acc[m][n][j] + bv;
        float gv = gelu_fast(v);
        if (OUT_F32)
          ((float*)Cv)[(size_t)(row0 + j) * N + col] = gv;
        else
          ((ushort*)Cv)[(size_t)(row0 + j) * N + col] = f2bf(gv);
      }
    }
  }
}

extern "C" void kernel_launch(void* const* d_in, const int* in_sizes, int n_in,
                              void* d_out, int out_size, void* d_ws, size_t ws_size,
                              hipStream_t stream) {
  const float* z   = (const float*)d_in[0];
  const float* att = (const float*)d_in[1];
  const float* Wptr[7] = {(const float*)d_in[2],  (const float*)d_in[4],
                          (const float*)d_in[6],  (const float*)d_in[8],
                          (const float*)d_in[10], (const float*)d_in[12],
                          (const float*)d_in[14]};
  const float* bptr[7] = {(const float*)d_in[3],  (const float*)d_in[5],
                          (const float*)d_in[7],  (const float*)d_in[9],
                          (const float*)d_in[11], (const float*)d_in[13],
                          (const float*)d_in[15]};
  const int Ns[7] = {1024, 512, 256, 256, 512, 1024, 2048};
  const int Ks[7] = {2048, 1024, 512, 256, 256, 512, 1024};
  const int M = 8192;

  char* ws = (char*)d_ws;
  ushort* bufA = (ushort*)ws;
  ushort* bufB = (ushort*)(ws + 33554432);
  ushort* qw   = (ushort*)(ws + 33554432 + 16777216);
  float* partials = (float*)(ws + 33554432 + 16777216 + 11141120);
  float* ig = partials + 7 * 64;

  WDesc wd;
  int cum = 0;
  size_t qoff[7]; size_t qc = 0;
  for (int l = 0; l < 7; ++l) {
    wd.W[l] = Wptr[l];
    int nv = Ns[l] * Ks[l] / 4;
    wd.nvec[l] = nv;
    wd.vcum[l] = cum;
    cum += nv;
    qoff[l] = qc;
    qc += (size_t)Ns[l] * Ks[l];
  }
  wd.vcum[7] = cum;

  const int qblks = (cum + 255) / 256;
  absmean_partial<<<dim3(64, 7), 256, 0, stream>>>(wd, partials);
  absmean_final<<<7, 64, 0, stream>>>(wd, partials, ig);
  prep_kernel<<<qblks + 8192, 256, 0, stream>>>(wd, ig, qw, z, att, bufA, qblks);

  ushort* inb = bufA; ushort* outb = bufB;
  // L0: 8192x1024, K=2048 -> pipe3 <BN=128>, grid (8,32)=256
  gemm_pipe3<128, false><<<dim3(Ns[0] / 128, M / 256), dim3(512), 0, stream>>>(
      inb, qw + qoff[0], bptr[0], outb, M, Ns[0], Ks[0]);
  { ushort* tmp = inb; inb = outb; outb = tmp; }
  // L1: 8192x512, K=1024 -> pipe3 <BN=64>, grid (8,32)=256
  gemm_pipe3<64, false><<<dim3(Ns[1] / 64, M / 256), dim3(512), 0, stream>>>(
      inb, qw + qoff[1], bptr[1], outb, M, Ns[1], Ks[1]);
  { ushort* tmp = inb; inb = outb; outb = tmp; }
  // L2: 8192x256, K=512 -> 2-phase <64,64>
  gemm_bt_bias_gelu<64, 64, false><<<dim3(Ns[2] / 64, M / 64), 256, 0, stream>>>(
      inb, qw + qoff[2], bptr[2], outb, M, Ns[2], Ks[2]);
  { ushort* tmp = inb; inb = outb; outb = tmp; }
  // L3: 8192x256, K=256 -> 2-phase <64,64>
  gemm_bt_bias_gelu<64, 64, false><<<dim3(Ns[3] / 64, M / 64), 256, 0, stream>>>(
      inb, qw + qoff[3], bptr[3], outb, M, Ns[3], Ks[3]);
  { ushort* tmp = inb; inb = outb; outb = tmp; }
  // L4: 8192x512, K=256 -> pipe3 <BN=64>, grid (8,32)=256
  gemm_pipe3<64, false><<<dim3(Ns[4] / 64, M / 256), dim3(512), 0, stream>>>(
      inb, qw + qoff[4], bptr[4], outb, M, Ns[4], Ks[4]);
  { ushort* tmp = inb; inb = outb; outb = tmp; }
  // L5: 8192x1024, K=512 -> pipe3 <BN=128>, grid (8,32)
  gemm_pipe3<128, false><<<dim3(Ns[5] / 128, M / 256), dim3(512), 0, stream>>>(
      inb, qw + qoff[5], bptr[5], outb, M, Ns[5], Ks[5]);
  { ushort* tmp = inb; inb = outb; outb = tmp; }
  // L6: 8192x2048, K=1024 -> 2-phase <128,128>, grid (16,64)=1024 blocks,
  // 256 thr, 32 KB LDS -> ~4 blk/CU. R2 theory: 1-blk/CU lockstep caps
  // MfmaUtil at 25% (669 TF); cross-block overlap (m114/m97: 912 TF at
  // this exact structure) should hide the per-tile drain. fp32 out.
  gemm_bt_bias_gelu<128, 128, true><<<dim3(Ns[6] / 128, M / 128), 256, 0, stream>>>(
      inb, qw + qoff[6], bptr[6], d_out, M, Ns[6], Ks[6]);
}

// Round 4
// 186.231 us; speedup vs baseline: 1.1252x; 1.0018x over previous
//
#include <hip/hip_runtime.h>
#include <hip/hip_bf16.h>
#include <cstdint>

typedef __attribute__((ext_vector_type(8))) __bf16 bf16x8;
typedef __attribute__((ext_vector_type(4))) float f32x4;

typedef __attribute__((address_space(1))) const void g_void;
typedef __attribute__((address_space(3))) void l_void;

__device__ __forceinline__ void gload_lds16(const void* g, void* l) {
  __builtin_amdgcn_global_load_lds((g_void*)(uintptr_t)g,
                                   (l_void*)(uint32_t)(uintptr_t)l, 16, 0, 0);
}

__device__ __forceinline__ ushort f2bf(float f) {
  union { float f; uint32_t u; } v; v.f = f;
  uint32_t r = v.u + 0x7fffu + ((v.u >> 16) & 1u);
  return (ushort)(r >> 16);
}

struct WDesc {
  const float* W[7];
  int nvec[7];
  int vcum[8];
};

// ---------- gamma = mean(|W|) + 1e-8, two-phase deterministic ----------
__global__ void absmean_partial(WDesc wd, float* __restrict__ partials) {
  __shared__ float red[256];
  const int layer = blockIdx.y;
  const float4* W = (const float4*)wd.W[layer];
  const int nv = wd.nvec[layer];
  float s = 0.f;
  for (int i = blockIdx.x * 256 + threadIdx.x; i < nv; i += gridDim.x * 256) {
    float4 w = W[i];
    s += fabsf(w.x) + fabsf(w.y) + fabsf(w.z) + fabsf(w.w);
  }
  red[threadIdx.x] = s;
  __syncthreads();
  for (int o = 128; o > 0; o >>= 1) {
    if (threadIdx.x < o) red[threadIdx.x] += red[threadIdx.x + o];
    __syncthreads();
  }
  if (threadIdx.x == 0) partials[layer * 64 + blockIdx.x] = red[0];
}

__global__ void absmean_final(WDesc wd, const float* __restrict__ partials,
                              float* __restrict__ ig) {
  const int layer = blockIdx.x;
  float v = partials[layer * 64 + threadIdx.x];
  for (int o = 32; o > 0; o >>= 1) v += __shfl_down(v, o, 64);
  if (threadIdx.x == 0) {
    float mean = v / (float)(wd.nvec[layer] * 4);
    ig[layer] = 1.0f / (mean + 1e-8f);
  }
}

// ---------- fused: ternary quantize (all layers) + concat->bf16 ----------
__global__ void prep_kernel(WDesc wd, const float* __restrict__ ig,
                            ushort* __restrict__ qw,
                            const float* __restrict__ z,
                            const float* __restrict__ att,
                            ushort* __restrict__ cat, int qblks) {
  if ((int)blockIdx.x < qblks) {
    const int v = blockIdx.x * 256 + threadIdx.x;
    if (v >= wd.vcum[7]) return;
    int layer = 0;
#pragma unroll
    for (int i = 1; i < 7; ++i) layer += (v >= wd.vcum[i]);
    const int lv = v - wd.vcum[layer];
    const float g = ig[layer];
    float4 w = ((const float4*)wd.W[layer])[lv];
    ushort4 o;
    o.x = f2bf(fmaxf(-1.f, fminf(1.f, rintf(w.x * g))));
    o.y = f2bf(fmaxf(-1.f, fminf(1.f, rintf(w.y * g))));
    o.z = f2bf(fmaxf(-1.f, fminf(1.f, rintf(w.z * g))));
    o.w = f2bf(fmaxf(-1.f, fminf(1.f, rintf(w.w * g))));
    ((ushort4*)qw)[v] = o;
  } else {
    const int tg = (blockIdx.x - qblks) * 256 + threadIdx.x;
    const int row = tg >> 8;
    const int k0 = (tg & 255) * 8;
    const float* src = (k0 < 1024) ? (z + (size_t)row * 1024 + k0)
                                   : (att + (size_t)row * 1024 + (k0 - 1024));
    float4 a = ((const float4*)src)[0];
    float4 b = ((const float4*)src)[1];
    ushort4 o0; o0.x = f2bf(a.x); o0.y = f2bf(a.y); o0.z = f2bf(a.z); o0.w = f2bf(a.w);
    ushort4 o1; o1.x = f2bf(b.x); o1.y = f2bf(b.y); o1.z = f2bf(b.z); o1.w = f2bf(b.w);
    ushort4* dst = (ushort4*)(cat + (size_t)tg * 8);
    dst[0] = o0; dst[1] = o1;
  }
}

// ---------- fast GELU (tanh form, branch-free) ----------
__device__ __forceinline__ float gelu_fast(float x) {
  float x2 = x * x;
  float u = x * fmaf(x2, 0.0356774081f, 0.7978845608f);
  float e = exp2f(u * 2.8853900818f);
  float r = __builtin_amdgcn_rcpf(e + 1.0f);
  return x - x * r;
}

#define SB0() __builtin_amdgcn_sched_barrier(0)
#define BAR() __builtin_amdgcn_s_barrier()
#define LGKM0() asm volatile("s_waitcnt lgkmcnt(0)" ::: "memory")
#define VMW(NN) asm volatile("s_waitcnt vmcnt(%0)" ::"n"(NN) : "memory")

// =====================================================================
// Triple-buffered 1-barrier-per-tile GEMM: BM=256, 8 waves (2M x 4N),
// BK=64, BN in {64,128}. R0-exact schedule (verified; do not touch).
// =====================================================================
template <int BN, bool OUT_F32>
__global__ __launch_bounds__(512, 2)
void gemm_pipe3(const ushort* __restrict__ A, const ushort* __restrict__ Bw,
                const float* __restrict__ bias, void* __restrict__ Cv,
                int M, int N, int K) {
  constexpr int BM = 256;
  constexpr int WN = BN / 4;             // 16 or 32
  constexpr int FM = 8;
  constexpr int FN = WN / 16;            // 1 or 2
  constexpr int HM = 4;
  constexpr int HN = 1;
  constexpr int SA = 4;                  // A 64-row chunks
  constexpr int SB = BN / 64;            // B 64-row chunks (1 or 2)
  constexpr int L = SA + SB;
  constexpr int TILE_USH = (BM + BN) * 64;

  __shared__ ushort lds[3 * TILE_USH];

  const int t = threadIdx.x;
  const int lane = t & 63, wid = t >> 6;
  const int wr = wid >> 2, wc = wid & 3;
  const int l15 = lane & 15, lhi = lane >> 4;

  const int gx = gridDim.x;
  const int nwg = gx * gridDim.y;
  int lin = blockIdx.y * gx + blockIdx.x;
  lin = (lin & 7) * (nwg >> 3) + (lin >> 3);  // XCD chunked (nwg % 8 == 0)
  const int bm0 = (lin / gx) * BM, bn0 = (lin % gx) * BN;

  const int NT = K >> 6;

  const int srow = t >> 3;
  const int scol = ((t & 7) ^ ((t >> 3) & 7)) * 8;

  auto stage = [&](int tile, int buf) {
    ushort* tb = &lds[buf * TILE_USH];
    const int kt = tile * 64;
#pragma unroll
    for (int c = 0; c < SA; ++c) {
      const int lr = c * 64 + srow;
      gload_lds16(A + (size_t)(bm0 + lr) * K + kt + scol,
                  &tb[lr * 64 + (t & 7) * 8]);
    }
#pragma unroll
    for (int c = 0; c < SB; ++c) {
      const int lr = c * 64 + srow;
      gload_lds16(Bw + (size_t)(bn0 + lr) * K + kt + scol,
                  &tb[BM * 64 + lr * 64 + (t & 7) * 8]);
    }
  };

  bf16x8 a[HM][2], b[HN][2];
  f32x4 acc[FM][FN] = {};

  auto loadA = [&](const ushort* tb, int mh) {
#pragma unroll
    for (int mi = 0; mi < HM; ++mi) {
      const int row = wr * 128 + (mh * HM + mi) * 16 + l15;
#pragma unroll
      for (int kh = 0; kh < 2; ++kh)
        a[mi][kh] =
            *(const bf16x8*)&tb[row * 64 + ((kh * 4 + lhi) ^ (l15 & 7)) * 8];
    }
  };
  auto loadB = [&](const ushort* tb, int nh) {
#pragma unroll
    for (int ni = 0; ni < HN; ++ni) {
      const int row = wc * WN + (nh * HN + ni) * 16 + l15;
#pragma unroll
      for (int kh = 0; kh < 2; ++kh)
        b[ni][kh] = *(const bf16x8*)&tb[BM * 64 + row * 64 +
                                        ((kh * 4 + lhi) ^ (l15 & 7)) * 8];
    }
  };

#define MFMA_(MH, NH)                                                        \
  {                                                                          \
    __builtin_amdgcn_s_setprio(1);                                           \
    _Pragma("unroll") for (int kh = 0; kh < 2; ++kh)                         \
    _Pragma("unroll") for (int mi = 0; mi < HM; ++mi)                        \
    _Pragma("unroll") for (int ni = 0; ni < HN; ++ni)                        \
      acc[(MH) * HM + mi][(NH) * HN + ni] =                                  \
          __builtin_amdgcn_mfma_f32_16x16x32_bf16(                           \
              a[mi][kh], b[ni][kh], acc[(MH) * HM + mi][(NH) * HN + ni],     \
              0, 0, 0);                                                      \
    __builtin_amdgcn_s_setprio(0);                                           \
  }

  // prologue: stage tiles 0,1 into bufs 0,1; wait tile 0; publish.
  stage(0, 0);
  stage(1, 1);
  VMW(L);
  BAR();
  SB0();

  int buf = 0, sbuf = 2;
  for (int tt = 0; tt < NT; ++tt) {
    const bool more = (tt + 2 < NT);
    if (more) stage(tt + 2, sbuf);
    const ushort* tb = &lds[buf * TILE_USH];
    if constexpr (FN == 2) {
      loadA(tb, 0); loadB(tb, 0);
      MFMA_(0, 0);
      loadB(tb, 1);
      MFMA_(0, 1);
      loadA(tb, 1);
      MFMA_(1, 1);
      loadB(tb, 0);
      MFMA_(1, 0);
    } else {
      loadA(tb, 0); loadB(tb, 0);
      MFMA_(0, 0);
      loadA(tb, 1);
      MFMA_(1, 0);
    }
    SB0();
    if (more) { VMW(L); } else { VMW(0); }
    BAR();
    SB0();
    buf = (buf == 2) ? 0 : buf + 1;
    sbuf = (sbuf == 2) ? 0 : sbuf + 1;
  }
#undef MFMA_

#pragma unroll
  for (int n = 0; n < FN; ++n) {
    const int col = bn0 + wc * WN + n * 16 + l15;
    const float bv = bias[col];
#pragma unroll
    for (int m = 0; m < FM; ++m) {
      const int row0 = bm0 + wr * 128 + m * 16 + lhi * 4;
#pragma unroll
      for (int j = 0; j < 4; ++j) {
        float v = acc[m][n][j] + bv;
        float gv = gelu_fast(v);
        if (OUT_F32)
          ((float*)Cv)[(size_t)(row0 + j) * N + col] = gv;
        else
          ((ushort*)Cv)[(size_t)(row0 + j) * N + col] = f2bf(gv);
      }
    }
  }
}

// =====================================================================
// R3: 8-phase (4 phases/K-tile) counted-vmcnt GEMM, BM=BN=256, BK=64,
// 8 waves (2M x 4N), per-wave C = 128x64 in 4 quadrants of 64x32.
// Phase = {ds_read own quadrant; stage one 128-row piece of tile J+1
// into the other buffer; BAR; LGKM0; 16 MFMA; [counted VMW]; BAR}.
//
// Hazard ledger:
//  * RAW (stage->read): piece staged during tile J is read during tile
//    J+1. Reads of {B0,B1,A0} at J+1.Ph1 are protected by VMW(2)+BAR at
//    J.Ph4-end (retires the oldest 6 of the 8 outstanding loads = B0,B1,
//    A0; the following BAR upgrades my-wave-landed to all-waves-landed).
//    Read of A1 at J+1.Ph3 is protected by VMW(4)+BAR at J+1.Ph2-end
//    (outstanding there = A1(J+1),B0(J+2),B1(J+2) = 6; retires A1).
//  * WAR (read->stage): stages into buf P^1 issue at tile J's phases;
//    buf P^1's previous tile J-1 was fully ds_read-retired at each
//    wave's J-1.Ph4 LGKM0, which precedes J-1.Ph4's trailing BAR, which
//    precedes any tile-J instruction. gload LDS-writes cannot complete
//    before issue -> no write can precede those retired reads.
//  * All barriers in uniform control flow (J, `more` wave-uniform).
// Piece issue order per tile: B0, B1, A0, A1 (vmcnt is issue-ordered).
// =====================================================================
template <bool OUT_F32>
__global__ __launch_bounds__(512, 1)
void gemm_8ph(const ushort* __restrict__ A, const ushort* __restrict__ Bw,
              const float* __restrict__ bias, void* __restrict__ Cv,
              int M, int N, int K) {
  constexpr int BM = 256;
  constexpr int BN = 256;
  constexpr int WN = 64;
  constexpr int FM = 8;
  constexpr int FN = 4;
  constexpr int HM = 4;
  constexpr int HN = 2;
  constexpr int TILE_USH = (BM + BN) * 64;

  __shared__ ushort lds[2 * TILE_USH];

  const int t = threadIdx.x;
  const int lane = t & 63, wid = t >> 6;
  const int wr = wid >> 2, wc = wid & 3;
  const int l15 = lane & 15, lhi = lane >> 4;

  const int gx = gridDim.x;
  const int nwg = gx * gridDim.y;
  int lin = blockIdx.y * gx + blockIdx.x;
  lin = (lin & 7) * (nwg >> 3) + (lin >> 3);  // nwg=256, %8==0
  const int bm0 = (lin / gx) * BM, bn0 = (lin % gx) * BN;

  const int NT = K >> 6;

  const int srow = t >> 3;
  const int scol = ((t & 7) ^ ((t >> 3) & 7)) * 8;

  // piece stagers: h selects the 128-row half (2 x 64-row chunks = 2 loads)
  auto stageA2 = [&](ushort* tb, int kt, int h) {
#pragma unroll
    for (int c = 0; c < 2; ++c) {
      const int lr = h * 128 + c * 64 + srow;
      gload_lds16(A + (size_t)(bm0 + lr) * K + kt + scol,
                  &tb[lr * 64 + (t & 7) * 8]);
    }
  };
  auto stageB2 = [&](ushort* tb, int kt, int h) {
#pragma unroll
    for (int c = 0; c < 2; ++c) {
      const int lr = h * 128 + c * 64 + srow;
      gload_lds16(Bw + (size_t)(bn0 + lr) * K + kt + scol,
                  &tb[BM * 64 + lr * 64 + (t & 7) * 8]);
    }
  };

  bf16x8 a[HM][2], b[HN][2];
  f32x4 acc[FM][FN] = {};

  auto loadA = [&](const ushort* tb, int mh) {
#pragma unroll
    for (int mi = 0; mi < HM; ++mi) {
      const int row = wr * 128 + (mh * HM + mi) * 16 + l15;
#pragma unroll
      for (int kh = 0; kh < 2; ++kh)
        a[mi][kh] =
            *(const bf16x8*)&tb[row * 64 + ((kh * 4 + lhi) ^ (l15 & 7)) * 8];
    }
  };
  auto loadB = [&](const ushort* tb, int nh) {
#pragma unroll
    for (int ni = 0; ni < HN; ++ni) {
      const int row = wc * WN + (nh * HN + ni) * 16 + l15;
#pragma unroll
      for (int kh = 0; kh < 2; ++kh)
        b[ni][kh] = *(const bf16x8*)&tb[BM * 64 + row * 64 +
                                        ((kh * 4 + lhi) ^ (l15 & 7)) * 8];
    }
  };

#define MFMA_(MH, NH)                                                        \
  {                                                                          \
    __builtin_amdgcn_s_setprio(1);                                           \
    _Pragma("unroll") for (int kh = 0; kh < 2; ++kh)                         \
    _Pragma("unroll") for (int mi = 0; mi < HM; ++mi)                        \
    _Pragma("unroll") for (int ni = 0; ni < HN; ++ni)                        \
      acc[(MH) * HM + mi][(NH) * HN + ni] =                                  \
          __builtin_amdgcn_mfma_f32_16x16x32_bf16(                           \
              a[mi][kh], b[ni][kh], acc[(MH) * HM + mi][(NH) * HN + ni],     \
              0, 0, 0);                                                      \
    __builtin_amdgcn_s_setprio(0);                                           \
  }

  // prologue: stage tile 0 in piece order B0,B1,A0,A1; publish B0,B1,A0.
  stageB2(&lds[0], 0, 0);
  stageB2(&lds[0], 0, 1);
  stageA2(&lds[0], 0, 0);
  stageA2(&lds[0], 0, 1);
  VMW(2);
  BAR();
  SB0();

  for (int J = 0; J < NT; ++J) {
    const ushort* tb = &lds[(J & 1) * TILE_USH];
    ushort* sb = &lds[((J & 1) ^ 1) * TILE_USH];
    const int kt2 = (J + 1) << 6;
    const bool more = (J + 1) < NT;

    // Ph1: Q1=(0,0) -- needs A0-sub + B0|B1-sub (VMW(2)+BAR last tile)
    loadA(tb, 0);
    loadB(tb, 0);
    if (more) stageB2(sb, kt2, 0);
    BAR();
    LGKM0();
    SB0();
    MFMA_(0, 0);
    SB0();
    BAR();
    SB0();

    // Ph2: Q2=(0,1)
    loadB(tb, 1);
    if (more) stageB2(sb, kt2, 1);
    BAR();
    LGKM0();
    SB0();
    MFMA_(0, 1);
    SB0();
    if (more) { VMW(4); } else { VMW(0); }  // retire A1(J) before Ph3 reads
    BAR();
    SB0();

    // Ph3: Q3=(1,1)
    loadA(tb, 1);
    if (more) stageA2(sb, kt2, 0);
    BAR();
    LGKM0();
    SB0();
    MFMA_(1, 1);
    SB0();
    BAR();
    SB0();

    // Ph4: Q4=(1,0)
    loadB(tb, 0);
    if (more) stageA2(sb, kt2, 1);
    BAR();
    LGKM0();
    SB0();
    MFMA_(1, 0);
    SB0();
    if (more) { VMW(2); } else { VMW(0); }  // retire B0,B1,A0(J+1)
    BAR();
    SB0();
  }
#undef MFMA_

#pragma unroll
  for (int n = 0; n < FN; ++n) {
    const int col = bn0 + wc * WN + n * 16 + l15;
    const float bv = bias[col];
#pragma unroll
    for (int m = 0; m < FM; ++m) {
      const int row0 = bm0 + wr * 128 + m * 16 + lhi * 4;
#pragma unroll
      for (int j = 0; j < 4; ++j) {
        float v = acc[m][n][j] + bv;
        float gv = gelu_fast(v);
        if (OUT_F32)
          ((float*)Cv)[(size_t)(row0 + j) * N + col] = gv;
        else
          ((ushort*)Cv)[(size_t)(row0 + j) * N + col] = f2bf(gv);
      }
    }
  }
}

// ---------- 2-phase GEMM for small layers (proven R2 structure) ----------
template <int BM, int BN, bool OUT_F32>
__global__ __launch_bounds__(256, 4)
void gemm_bt_bias_gelu(const ushort* __restrict__ A, const ushort* __restrict__ Bw,
                       const float* __restrict__ bias, void* __restrict__ Cv,
                       int M, int N, int K) {
  constexpr int WTM = BM / 32;
  constexpr int WTN = BN / 32;
  __shared__ ushort As[BM * 64];
  __shared__ ushort Bs[BN * 64];
  const int t = threadIdx.x;
  const int lane = t & 63, wid = t >> 6;
  const int wr = wid >> 1, wc = wid & 1;
  const int l15 = lane & 15, lhi = lane >> 4;

  const int gx = gridDim.x;
  const int nwg = gx * gridDim.y;
  int lin = blockIdx.y * gx + blockIdx.x;
  if ((nwg & 7) == 0) lin = (lin & 7) * (nwg >> 3) + (lin >> 3);
  const int bm0 = (lin / gx) * BM, bn0 = (lin % gx) * BN;

  const ushort* Abase = A + (size_t)bm0 * K;
  const ushort* Bbase = Bw + (size_t)bn0 * K;

  f32x4 acc[WTM][WTN] = {};

  for (int kt = 0; kt < K; kt += 64) {
#pragma unroll
    for (int i = 0; i < BM / 32; ++i) {
      int c = i * 256 + t;
      int r = c >> 3, c8 = c & 7;
      gload_lds16(Abase + (size_t)r * K + kt + c8 * 8, &As[c * 8]);
    }
#pragma unroll
    for (int i = 0; i < BN / 32; ++i) {
      int c = i * 256 + t;
      int r = c >> 3, c8 = c & 7;
      gload_lds16(Bbase + (size_t)r * K + kt + c8 * 8, &Bs[c * 8]);
    }
    asm volatile("s_waitcnt vmcnt(0)" ::: "memory");
    __syncthreads();
#pragma unroll
    for (int kk = 0; kk < 64; kk += 32) {
      bf16x8 af[WTM], bfr[WTN];
#pragma unroll
      for (int m = 0; m < WTM; ++m)
        af[m] = *(const bf16x8*)&As[(wr * (BM / 2) + m * 16 + l15) * 64 + kk + lhi * 8];
#pragma unroll
      for (int n = 0; n < WTN; ++n)
        bfr[n] = *(const bf16x8*)&Bs[(wc * (BN / 2) + n * 16 + l15) * 64 + kk + lhi * 8];
#pragma unroll
      for (int m = 0; m < WTM; ++m)
#pragma unroll
        for (int n = 0; n < WTN; ++n)
          acc[m][n] = __builtin_amdgcn_mfma_f32_16x16x32_bf16(af[m], bfr[n], acc[m][n], 0, 0, 0);
    }
    __syncthreads();
  }

#pragma unroll
  for (int n = 0; n < WTN; ++n) {
    const int col = bn0 + wc * (BN / 2) + n * 16 + l15;
    const float bv = bias[col];
#pragma unroll
    for (int m = 0; m < WTM; ++m) {
      const int row0 = bm0 + wr * (BM / 2) + m * 16 + lhi * 4;
#pragma unroll
      for (int j = 0; j < 4; ++j) {
        float v = acc[m][n][j] + bv;
        float gv = gelu_fast(v);
        if (OUT_F32)
          ((float*)Cv)[(size_t)(row0 + j) * N + col] = gv;
        else
          ((ushort*)Cv)[(size_t)(row0 + j) * N + col] = f2bf(gv);
      }
    }
  }
}

extern "C" void kernel_launch(void* const* d_in, const int* in_sizes, int n_in,
                              void* d_out, int out_size, void* d_ws, size_t ws_size,
                              hipStream_t stream) {
  const float* z   = (const float*)d_in[0];
  const float* att = (const float*)d_in[1];
  const float* Wptr[7] = {(const float*)d_in[2],  (const float*)d_in[4],
                          (const float*)d_in[6],  (const float*)d_in[8],
                          (const float*)d_in[10], (const float*)d_in[12],
                          (const float*)d_in[14]};
  const float* bptr[7] = {(const float*)d_in[3],  (const float*)d_in[5],
                          (const float*)d_in[7],  (const float*)d_in[9],
                          (const float*)d_in[11], (const float*)d_in[13],
                          (const float*)d_in[15]};
  const int Ns[7] = {1024, 512, 256, 256, 512, 1024, 2048};
  const int Ks[7] = {2048, 1024, 512, 256, 256, 512, 1024};
  const int M = 8192;

  char* ws = (char*)d_ws;
  ushort* bufA = (ushort*)ws;
  ushort* bufB = (ushort*)(ws + 33554432);
  ushort* qw   = (ushort*)(ws + 33554432 + 16777216);
  float* partials = (float*)(ws + 33554432 + 16777216 + 11141120);
  float* ig = partials + 7 * 64;

  WDesc wd;
  int cum = 0;
  size_t qoff[7]; size_t qc = 0;
  for (int l = 0; l < 7; ++l) {
    wd.W[l] = Wptr[l];
    int nv = Ns[l] * Ks[l] / 4;
    wd.nvec[l] = nv;
    wd.vcum[l] = cum;
    cum += nv;
    qoff[l] = qc;
    qc += (size_t)Ns[l] * Ks[l];
  }
  wd.vcum[7] = cum;

  const int qblks = (cum + 255) / 256;
  absmean_partial<<<dim3(64, 7), 256, 0, stream>>>(wd, partials);
  absmean_final<<<7, 64, 0, stream>>>(wd, partials, ig);
  prep_kernel<<<qblks + 8192, 256, 0, stream>>>(wd, ig, qw, z, att, bufA, qblks);

  ushort* inb = bufA; ushort* outb = bufB;
  // L0: 8192x1024, K=2048 -> pipe3 <BN=128>, grid (8,32)=256
  gemm_pipe3<128, false><<<dim3(Ns[0] / 128, M / 256), dim3(512), 0, stream>>>(
      inb, qw + qoff[0], bptr[0], outb, M, Ns[0], Ks[0]);
  { ushort* tmp = inb; inb = outb; outb = tmp; }
  // L1: 8192x512, K=1024 -> pipe3 <BN=64>, grid (8,32)=256
  gemm_pipe3<64, false><<<dim3(Ns[1] / 64, M / 256), dim3(512), 0, stream>>>(
      inb, qw + qoff[1], bptr[1], outb, M, Ns[1], Ks[1]);
  { ushort* tmp = inb; inb = outb; outb = tmp; }
  // L2: 8192x256, K=512 -> 2-phase <64,64>
  gemm_bt_bias_gelu<64, 64, false><<<dim3(Ns[2] / 64, M / 64), 256, 0, stream>>>(
      inb, qw + qoff[2], bptr[2], outb, M, Ns[2], Ks[2]);
  { ushort* tmp = inb; inb = outb; outb = tmp; }
  // L3: 8192x256, K=256 -> 2-phase <64,64>
  gemm_bt_bias_gelu<64, 64, false><<<dim3(Ns[3] / 64, M / 64), 256, 0, stream>>>(
      inb, qw + qoff[3], bptr[3], outb, M, Ns[3], Ks[3]);
  { ushort* tmp = inb; inb = outb; outb = tmp; }
  // L4: 8192x512, K=256 -> pipe3 <BN=64>, grid (8,32)=256
  gemm_pipe3<64, false><<<dim3(Ns[4] / 64, M / 256), dim3(512), 0, stream>>>(
      inb, qw + qoff[4], bptr[4], outb, M, Ns[4], Ks[4]);
  { ushort* tmp = inb; inb = outb; outb = tmp; }
  // L5: 8192x1024, K=512 -> pipe3 <BN=128>, grid (8,32)
  gemm_pipe3<128, false><<<dim3(Ns[5] / 128, M / 256), dim3(512), 0, stream>>>(
      inb, qw + qoff[5], bptr[5], outb, M, Ns[5], Ks[5]);
  { ushort* tmp = inb; inb = outb; outb = tmp; }
  // L6: 8192x2048, K=1024 -> 8-phase counted-vmcnt 256^2, grid (8,32)=256.
  // R3 theory: all simple 2-phase-class schedules cap at ~685 TF here
  // (three structures converged); T3+T4 counted-vmcnt phase pipeline is
  // the documented escape (m196/m218: +28-41%). fp32 out.
  gemm_8ph<true><<<dim3(Ns[6] / 256, M / 256), dim3(512), 0, stream>>>(
      inb, qw + qoff[6], bptr[6], d_out, M, Ns[6], Ks[6]);
}

// Round 5
// 184.579 us; speedup vs baseline: 1.1353x; 1.0089x over previous
//
#include <hip/hip_runtime.h>
#include <hip/hip_bf16.h>
#include <cstdint>

typedef __attribute__((ext_vector_type(8))) __bf16 bf16x8;
typedef __attribute__((ext_vector_type(4))) float f32x4;

typedef __attribute__((address_space(1))) const void g_void;
typedef __attribute__((address_space(3))) void l_void;

__device__ __forceinline__ void gload_lds16(const void* g, void* l) {
  __builtin_amdgcn_global_load_lds((g_void*)(uintptr_t)g,
                                   (l_void*)(uint32_t)(uintptr_t)l, 16, 0, 0);
}

__device__ __forceinline__ ushort f2bf(float f) {
  union { float f; uint32_t u; } v; v.f = f;
  uint32_t r = v.u + 0x7fffu + ((v.u >> 16) & 1u);
  return (ushort)(r >> 16);
}

struct WDesc {
  const float* W[7];
  int nvec[7];
  int vcum[8];
};

// ---------- gamma = mean(|W|) + 1e-8, two-phase deterministic ----------
__global__ void absmean_partial(WDesc wd, float* __restrict__ partials) {
  __shared__ float red[256];
  const int layer = blockIdx.y;
  const float4* W = (const float4*)wd.W[layer];
  const int nv = wd.nvec[layer];
  float s = 0.f;
  for (int i = blockIdx.x * 256 + threadIdx.x; i < nv; i += gridDim.x * 256) {
    float4 w = W[i];
    s += fabsf(w.x) + fabsf(w.y) + fabsf(w.z) + fabsf(w.w);
  }
  red[threadIdx.x] = s;
  __syncthreads();
  for (int o = 128; o > 0; o >>= 1) {
    if (threadIdx.x < o) red[threadIdx.x] += red[threadIdx.x + o];
    __syncthreads();
  }
  if (threadIdx.x == 0) partials[layer * 64 + blockIdx.x] = red[0];
}

__global__ void absmean_final(WDesc wd, const float* __restrict__ partials,
                              float* __restrict__ ig) {
  const int layer = blockIdx.x;
  float v = partials[layer * 64 + threadIdx.x];
  for (int o = 32; o > 0; o >>= 1) v += __shfl_down(v, o, 64);
  if (threadIdx.x == 0) {
    float mean = v / (float)(wd.nvec[layer] * 4);
    ig[layer] = 1.0f / (mean + 1e-8f);
  }
}

// ---------- fused: ternary quantize (all layers) + concat->bf16 ----------
__global__ void prep_kernel(WDesc wd, const float* __restrict__ ig,
                            ushort* __restrict__ qw,
                            const float* __restrict__ z,
                            const float* __restrict__ att,
                            ushort* __restrict__ cat, int qblks) {
  if ((int)blockIdx.x < qblks) {
    const int v = blockIdx.x * 256 + threadIdx.x;
    if (v >= wd.vcum[7]) return;
    int layer = 0;
#pragma unroll
    for (int i = 1; i < 7; ++i) layer += (v >= wd.vcum[i]);
    const int lv = v - wd.vcum[layer];
    const float g = ig[layer];
    float4 w = ((const float4*)wd.W[layer])[lv];
    ushort4 o;
    o.x = f2bf(fmaxf(-1.f, fminf(1.f, rintf(w.x * g))));
    o.y = f2bf(fmaxf(-1.f, fminf(1.f, rintf(w.y * g))));
    o.z = f2bf(fmaxf(-1.f, fminf(1.f, rintf(w.z * g))));
    o.w = f2bf(fmaxf(-1.f, fminf(1.f, rintf(w.w * g))));
    ((ushort4*)qw)[v] = o;
  } else {
    const int tg = (blockIdx.x - qblks) * 256 + threadIdx.x;
    const int row = tg >> 8;
    const int k0 = (tg & 255) * 8;
    const float* src = (k0 < 1024) ? (z + (size_t)row * 1024 + k0)
                                   : (att + (size_t)row * 1024 + (k0 - 1024));
    float4 a = ((const float4*)src)[0];
    float4 b = ((const float4*)src)[1];
    ushort4 o0; o0.x = f2bf(a.x); o0.y = f2bf(a.y); o0.z = f2bf(a.z); o0.w = f2bf(a.w);
    ushort4 o1; o1.x = f2bf(b.x); o1.y = f2bf(b.y); o1.z = f2bf(b.z); o1.w = f2bf(b.w);
    ushort4* dst = (ushort4*)(cat + (size_t)tg * 8);
    dst[0] = o0; dst[1] = o1;
  }
}

// ---------- fast GELU (tanh form, branch-free) ----------
__device__ __forceinline__ float gelu_fast(float x) {
  float x2 = x * x;
  float u = x * fmaf(x2, 0.0356774081f, 0.7978845608f);
  float e = exp2f(u * 2.8853900818f);
  float r = __builtin_amdgcn_rcpf(e + 1.0f);
  return x - x * r;
}

#define SB0() __builtin_amdgcn_sched_barrier(0)
#define BAR() __builtin_amdgcn_s_barrier()
#define LGKM0() asm volatile("s_waitcnt lgkmcnt(0)" ::: "memory")
#define VMW(NN) asm volatile("s_waitcnt vmcnt(%0)" ::"n"(NN) : "memory")

// =====================================================================
// Triple-buffered 1-barrier-per-tile GEMM: BM=256, 8 waves (2M x 4N),
// BK=64, BN in {64,128}. R0-exact schedule (verified; do not touch).
// =====================================================================
template <int BN, bool OUT_F32>
__global__ __launch_bounds__(512, 2)
void gemm_pipe3(const ushort* __restrict__ A, const ushort* __restrict__ Bw,
                const float* __restrict__ bias, void* __restrict__ Cv,
                int M, int N, int K) {
  constexpr int BM = 256;
  constexpr int WN = BN / 4;             // 16 or 32
  constexpr int FM = 8;
  constexpr int FN = WN / 16;            // 1 or 2
  constexpr int HM = 4;
  constexpr int HN = 1;
  constexpr int SA = 4;                  // A 64-row chunks
  constexpr int SB = BN / 64;            // B 64-row chunks (1 or 2)
  constexpr int L = SA + SB;
  constexpr int TILE_USH = (BM + BN) * 64;

  __shared__ ushort lds[3 * TILE_USH];

  const int t = threadIdx.x;
  const int lane = t & 63, wid = t >> 6;
  const int wr = wid >> 2, wc = wid & 3;
  const int l15 = lane & 15, lhi = lane >> 4;

  const int gx = gridDim.x;
  const int nwg = gx * gridDim.y;
  int lin = blockIdx.y * gx + blockIdx.x;
  lin = (lin & 7) * (nwg >> 3) + (lin >> 3);  // XCD chunked (nwg % 8 == 0)
  const int bm0 = (lin / gx) * BM, bn0 = (lin % gx) * BN;

  const int NT = K >> 6;

  const int srow = t >> 3;
  const int scol = ((t & 7) ^ ((t >> 3) & 7)) * 8;

  auto stage = [&](int tile, int buf) {
    ushort* tb = &lds[buf * TILE_USH];
    const int kt = tile * 64;
#pragma unroll
    for (int c = 0; c < SA; ++c) {
      const int lr = c * 64 + srow;
      gload_lds16(A + (size_t)(bm0 + lr) * K + kt + scol,
                  &tb[lr * 64 + (t & 7) * 8]);
    }
#pragma unroll
    for (int c = 0; c < SB; ++c) {
      const int lr = c * 64 + srow;
      gload_lds16(Bw + (size_t)(bn0 + lr) * K + kt + scol,
                  &tb[BM * 64 + lr * 64 + (t & 7) * 8]);
    }
  };

  bf16x8 a[HM][2], b[HN][2];
  f32x4 acc[FM][FN] = {};

  auto loadA = [&](const ushort* tb, int mh) {
#pragma unroll
    for (int mi = 0; mi < HM; ++mi) {
      const int row = wr * 128 + (mh * HM + mi) * 16 + l15;
#pragma unroll
      for (int kh = 0; kh < 2; ++kh)
        a[mi][kh] =
            *(const bf16x8*)&tb[row * 64 + ((kh * 4 + lhi) ^ (l15 & 7)) * 8];
    }
  };
  auto loadB = [&](const ushort* tb, int nh) {
#pragma unroll
    for (int ni = 0; ni < HN; ++ni) {
      const int row = wc * WN + (nh * HN + ni) * 16 + l15;
#pragma unroll
      for (int kh = 0; kh < 2; ++kh)
        b[ni][kh] = *(const bf16x8*)&tb[BM * 64 + row * 64 +
                                        ((kh * 4 + lhi) ^ (l15 & 7)) * 8];
    }
  };

#define MFMA_(MH, NH)                                                        \
  {                                                                          \
    __builtin_amdgcn_s_setprio(1);                                           \
    _Pragma("unroll") for (int kh = 0; kh < 2; ++kh)                         \
    _Pragma("unroll") for (int mi = 0; mi < HM; ++mi)                        \
    _Pragma("unroll") for (int ni = 0; ni < HN; ++ni)                        \
      acc[(MH) * HM + mi][(NH) * HN + ni] =                                  \
          __builtin_amdgcn_mfma_f32_16x16x32_bf16(                           \
              a[mi][kh], b[ni][kh], acc[(MH) * HM + mi][(NH) * HN + ni],     \
              0, 0, 0);                                                      \
    __builtin_amdgcn_s_setprio(0);                                           \
  }

  // prologue: stage tiles 0,1 into bufs 0,1; wait tile 0; publish.
  stage(0, 0);
  stage(1, 1);
  VMW(L);
  BAR();
  SB0();

  int buf = 0, sbuf = 2;
  for (int tt = 0; tt < NT; ++tt) {
    const bool more = (tt + 2 < NT);
    if (more) stage(tt + 2, sbuf);
    const ushort* tb = &lds[buf * TILE_USH];
    if constexpr (FN == 2) {
      loadA(tb, 0); loadB(tb, 0);
      MFMA_(0, 0);
      loadB(tb, 1);
      MFMA_(0, 1);
      loadA(tb, 1);
      MFMA_(1, 1);
      loadB(tb, 0);
      MFMA_(1, 0);
    } else {
      loadA(tb, 0); loadB(tb, 0);
      MFMA_(0, 0);
      loadA(tb, 1);
      MFMA_(1, 0);
    }
    SB0();
    if (more) { VMW(L); } else { VMW(0); }
    BAR();
    SB0();
    buf = (buf == 2) ? 0 : buf + 1;
    sbuf = (sbuf == 2) ? 0 : sbuf + 1;
  }
#undef MFMA_

#pragma unroll
  for (int n = 0; n < FN; ++n) {
    const int col = bn0 + wc * WN + n * 16 + l15;
    const float bv = bias[col];
#pragma unroll
    for (int m = 0; m < FM; ++m) {
      const int row0 = bm0 + wr * 128 + m * 16 + lhi * 4;
#pragma unroll
      for (int j = 0; j < 4; ++j) {
        float v = acc[m][n][j] + bv;
        float gv = gelu_fast(v);
        if (OUT_F32)
          ((float*)Cv)[(size_t)(row0 + j) * N + col] = gv;
        else
          ((ushort*)Cv)[(size_t)(row0 + j) * N + col] = f2bf(gv);
      }
    }
  }
}

// =====================================================================
// R4: deep-pipelined 8-phase GEMM (m201 mechanism, corrected port).
// BM=BN=256, BK=64, 8 waves (2M x 4N). Per wave: C = 128x64.
//
// KEY STRUCTURE (what R3 got wrong):
//  * Each wave reads ALL its K-tile fragments in phases 1-2 and holds
//    them in regs (a[2][4][2], b[2][2][2]); per-wave rows align exactly
//    with 128-row halves (wr <-> A-half, wc>>1 <-> B-half), so after
//    phase-2's trailing barrier the tile's LDS buffer is GLOBALLY DEAD.
//  * Phases 3-4 are pure-register MFMA; their stages write tile J+2's
//    A-halves into the CURRENT buffer (dead since ph2-barrier) -> a
//    continuous half-tile stream staged ~6 phases ahead of consumption
//    with only 2 LDS buffers.
//  * ONE counted VMW(4) per K-tile (at ph4), retiring halves staged
//    1.5 tiles earlier -> real slack, no HBM-latency serialization.
//
// Stage stream (half = 128 rows = 2 gloads, issue order):
//   ... (J,A0)@J-2p3 (J,A1)@J-2p4 (J,B0)@J-1p1 (J,B1)@J-1p2
//       (J+1,A0)@J-1p3 (J+1,A1)@J-1p4 (J+1,B0)@Jp1 ...
// Hazard ledger:
//  * RAW: tile J reads (ph1/2) touch its 4 halves; VMW(4) at J-1.ph4
//    leaves newest 4 loads = (J+1,A0),(J+1,A1) -> retires through
//    (J,B1); trailing BAR upgrades to all-waves-landed.   [checked]
//  * WAR: (J+1,A0/A1) stages at J-1.ph3/4 overwrite buf((J+1)&1) =
//    tile J-1's own buffer, dead since J-1.ph2 trailing BAR (all
//    waves' reads LGKM0-retired before it).                [checked]
//  * Tail: when J+2 >= NT the ph3/4 stages are skipped, so VMW(4)
//    would under-retire -> use VMW(0) there (J=NT-2 drains tile
//    NT-1's B-halves; J=NT-1 no-op).                       [checked]
//  * All barriers in uniform control flow (J, s1, s2 wave-uniform;
//    stages inside branches, barriers outside).
// =====================================================================
template <bool OUT_F32>
__global__ __launch_bounds__(512, 2)
void gemm_8p2(const ushort* __restrict__ A, const ushort* __restrict__ Bw,
              const float* __restrict__ bias, void* __restrict__ Cv,
              int M, int N, int K) {
  constexpr int BM = 256;
  constexpr int BN = 256;
  constexpr int TILE_USH = (BM + BN) * 64;

  __shared__ ushort lds[2 * TILE_USH];

  const int t = threadIdx.x;
  const int lane = t & 63, wid = t >> 6;
  const int wr = wid >> 2, wc = wid & 3;
  const int l15 = lane & 15, lhi = lane >> 4;

  const int gx = gridDim.x;
  const int nwg = gx * gridDim.y;
  int lin = blockIdx.y * gx + blockIdx.x;
  lin = (lin & 7) * (nwg >> 3) + (lin >> 3);  // nwg=256, %8==0
  const int bm0 = (lin / gx) * BM, bn0 = (lin % gx) * BN;

  const int NT = K >> 6;

  const int srow = t >> 3;
  const int scol = ((t & 7) ^ ((t >> 3) & 7)) * 8;

  // stage half h (128 rows, 2 gloads) of A/B for K-tile kt into buffer tb
  auto stageA = [&](ushort* tb, int kt, int h) {
#pragma unroll
    for (int c = 0; c < 2; ++c) {
      const int lr = h * 128 + c * 64 + srow;
      gload_lds16(A + (size_t)(bm0 + lr) * K + kt * 64 + scol,
                  &tb[lr * 64 + (t & 7) * 8]);
    }
  };
  auto stageB = [&](ushort* tb, int kt, int h) {
#pragma unroll
    for (int c = 0; c < 2; ++c) {
      const int lr = h * 128 + c * 64 + srow;
      gload_lds16(Bw + (size_t)(bn0 + lr) * K + kt * 64 + scol,
                  &tb[BM * 64 + lr * 64 + (t & 7) * 8]);
    }
  };

  bf16x8 a[2][4][2];   // [mh][mi][kh] -- full per-wave A for one K-tile
  bf16x8 b[2][2][2];   // [nh][ni][kh] -- full per-wave B for one K-tile
  f32x4 acc[8][4] = {};

  auto loadA = [&](const ushort* tb, int mh) {
#pragma unroll
    for (int mi = 0; mi < 4; ++mi) {
      const int row = wr * 128 + mh * 64 + mi * 16 + l15;
#pragma unroll
      for (int kh = 0; kh < 2; ++kh)
        a[mh][mi][kh] =
            *(const bf16x8*)&tb[row * 64 + ((kh * 4 + lhi) ^ (l15 & 7)) * 8];
    }
  };
  auto loadB = [&](const ushort* tb, int nh) {
#pragma unroll
    for (int ni = 0; ni < 2; ++ni) {
      const int row = wc * 64 + nh * 32 + ni * 16 + l15;
#pragma unroll
      for (int kh = 0; kh < 2; ++kh)
        b[nh][ni][kh] = *(const bf16x8*)&tb[BM * 64 + row * 64 +
                                            ((kh * 4 + lhi) ^ (l15 & 7)) * 8];
    }
  };

#define MFMA_(MH, NH)                                                        \
  {                                                                          \
    __builtin_amdgcn_s_setprio(1);                                           \
    _Pragma("unroll") for (int kh = 0; kh < 2; ++kh)                         \
    _Pragma("unroll") for (int mi = 0; mi < 4; ++mi)                         \
    _Pragma("unroll") for (int ni = 0; ni < 2; ++ni)                         \
      acc[(MH) * 4 + mi][(NH) * 2 + ni] =                                    \
          __builtin_amdgcn_mfma_f32_16x16x32_bf16(                           \
              a[(MH)][mi][kh], b[(NH)][ni][kh],                              \
              acc[(MH) * 4 + mi][(NH) * 2 + ni], 0, 0, 0);                   \
    __builtin_amdgcn_s_setprio(0);                                           \
  }

  // prologue: tile0 fully + tile1 A-halves; VMW(4) lands tile0, leaves
  // (1,A0),(1,A1) in flight -- matches steady-state stream order.
  {
    ushort* b0 = &lds[0];
    ushort* b1 = &lds[TILE_USH];
    stageA(b0, 0, 0); stageA(b0, 0, 1);
    stageB(b0, 0, 0); stageB(b0, 0, 1);
    stageA(b1, 1, 0); stageA(b1, 1, 1);
    VMW(4);
    BAR();
    SB0();
  }

  for (int J = 0; J < NT; ++J) {
    const ushort* tb = &lds[(J & 1) * TILE_USH];          // read tile J
    ushort* cb = &lds[(J & 1) * TILE_USH];                // J+2 A-halves (dead after ph2)
    ushort* sb = &lds[((J + 1) & 1) * TILE_USH];          // J+1 B-halves
    const bool s1 = (J + 1) < NT;
    const bool s2 = (J + 2) < NT;

    // Ph1: read A-lo + B-lo (12 ds_reads); stage (J+1,B0); MFMA Q(0,0)
    loadA(tb, 0);
    loadB(tb, 0);
    if (s1) stageB(sb, J + 1, 0);
    BAR();
    LGKM0();
    SB0();
    MFMA_(0, 0);
    SB0();
    BAR();
    SB0();

    // Ph2: read A-hi + B-hi (12 ds_reads); stage (J+1,B1); MFMA Q(1,1)
    // After this phase's trailing barrier, tile J's buffer is DEAD.
    loadA(tb, 1);
    loadB(tb, 1);
    if (s1) stageB(sb, J + 1, 1);
    BAR();
    LGKM0();
    SB0();
    MFMA_(1, 1);
    SB0();
    BAR();
    SB0();

    // Ph3: pure-reg MFMA Q(0,1); stage (J+2,A0) into current (dead) buf
    if (s2) stageA(cb, J + 2, 0);
    BAR();
    SB0();
    MFMA_(0, 1);
    SB0();
    BAR();
    SB0();

    // Ph4: pure-reg MFMA Q(1,0); stage (J+2,A1); counted wait
    if (s2) stageA(cb, J + 2, 1);
    BAR();
    SB0();
    MFMA_(1, 0);
    SB0();
    if (s2) { VMW(4); } else { VMW(0); }
    BAR();
    SB0();
  }
#undef MFMA_

#pragma unroll
  for (int n = 0; n < 4; ++n) {
    const int col = bn0 + wc * 64 + n * 16 + l15;
    const float bv = bias[col];
#pragma unroll
    for (int m = 0; m < 8; ++m) {
      const int row0 = bm0 + wr * 128 + m * 16 + lhi * 4;
#pragma unroll
      for (int j = 0; j < 4; ++j) {
        float v = acc[m][n][j] + bv;
        float gv = gelu_fast(v);
        if (OUT_F32)
          ((float*)Cv)[(size_t)(row0 + j) * N + col] = gv;
        else
          ((ushort*)Cv)[(size_t)(row0 + j) * N + col] = f2bf(gv);
      }
    }
  }
}

// ---------- 2-phase GEMM for small layers (proven R2 structure) ----------
template <int BM, int BN, bool OUT_F32>
__global__ __launch_bounds__(256, 4)
void gemm_bt_bias_gelu(const ushort* __restrict__ A, const ushort* __restrict__ Bw,
                       const float* __restrict__ bias, void* __restrict__ Cv,
                       int M, int N, int K) {
  constexpr int WTM = BM / 32;
  constexpr int WTN = BN / 32;
  __shared__ ushort As[BM * 64];
  __shared__ ushort Bs[BN * 64];
  const int t = threadIdx.x;
  const int lane = t & 63, wid = t >> 6;
  const int wr = wid >> 1, wc = wid & 1;
  const int l15 = lane & 15, lhi = lane >> 4;

  const int gx = gridDim.x;
  const int nwg = gx * gridDim.y;
  int lin = blockIdx.y * gx + blockIdx.x;
  if ((nwg & 7) == 0) lin = (lin & 7) * (nwg >> 3) + (lin >> 3);
  const int bm0 = (lin / gx) * BM, bn0 = (lin % gx) * BN;

  const ushort* Abase = A + (size_t)bm0 * K;
  const ushort* Bbase = Bw + (size_t)bn0 * K;

  f32x4 acc[WTM][WTN] = {};

  for (int kt = 0; kt < K; kt += 64) {
#pragma unroll
    for (int i = 0; i < BM / 32; ++i) {
      int c = i * 256 + t;
      int r = c >> 3, c8 = c & 7;
      gload_lds16(Abase + (size_t)r * K + kt + c8 * 8, &As[c * 8]);
    }
#pragma unroll
    for (int i = 0; i < BN / 32; ++i) {
      int c = i * 256 + t;
      int r = c >> 3, c8 = c & 7;
      gload_lds16(Bbase + (size_t)r * K + kt + c8 * 8, &Bs[c * 8]);
    }
    asm volatile("s_waitcnt vmcnt(0)" ::: "memory");
    __syncthreads();
#pragma unroll
    for (int kk = 0; kk < 64; kk += 32) {
      bf16x8 af[WTM], bfr[WTN];
#pragma unroll
      for (int m = 0; m < WTM; ++m)
        af[m] = *(const bf16x8*)&As[(wr * (BM / 2) + m * 16 + l15) * 64 + kk + lhi * 8];
#pragma unroll
      for (int n = 0; n < WTN; ++n)
        bfr[n] = *(const bf16x8*)&Bs[(wc * (BN / 2) + n * 16 + l15) * 64 + kk + lhi * 8];
#pragma unroll
      for (int m = 0; m < WTM; ++m)
#pragma unroll
        for (int n = 0; n < WTN; ++n)
          acc[m][n] = __builtin_amdgcn_mfma_f32_16x16x32_bf16(af[m], bfr[n], acc[m][n], 0, 0, 0);
    }
    __syncthreads();
  }

#pragma unroll
  for (int n = 0; n < WTN; ++n) {
    const int col = bn0 + wc * (BN / 2) + n * 16 + l15;
    const float bv = bias[col];
#pragma unroll
    for (int m = 0; m < WTM; ++m) {
      const int row0 = bm0 + wr * (BM / 2) + m * 16 + lhi * 4;
#pragma unroll
      for (int j = 0; j < 4; ++j) {
        float v = acc[m][n][j] + bv;
        float gv = gelu_fast(v);
        if (OUT_F32)
          ((float*)Cv)[(size_t)(row0 + j) * N + col] = gv;
        else
          ((ushort*)Cv)[(size_t)(row0 + j) * N + col] = f2bf(gv);
      }
    }
  }
}

extern "C" void kernel_launch(void* const* d_in, const int* in_sizes, int n_in,
                              void* d_out, int out_size, void* d_ws, size_t ws_size,
                              hipStream_t stream) {
  const float* z   = (const float*)d_in[0];
  const float* att = (const float*)d_in[1];
  const float* Wptr[7] = {(const float*)d_in[2],  (const float*)d_in[4],
                          (const float*)d_in[6],  (const float*)d_in[8],
                          (const float*)d_in[10], (const float*)d_in[12],
                          (const float*)d_in[14]};
  const float* bptr[7] = {(const float*)d_in[3],  (const float*)d_in[5],
                          (const float*)d_in[7],  (const float*)d_in[9],
                          (const float*)d_in[11], (const float*)d_in[13],
                          (const float*)d_in[15]};
  const int Ns[7] = {1024, 512, 256, 256, 512, 1024, 2048};
  const int Ks[7] = {2048, 1024, 512, 256, 256, 512, 1024};
  const int M = 8192;

  char* ws = (char*)d_ws;
  ushort* bufA = (ushort*)ws;
  ushort* bufB = (ushort*)(ws + 33554432);
  ushort* qw   = (ushort*)(ws + 33554432 + 16777216);
  float* partials = (float*)(ws + 33554432 + 16777216 + 11141120);
  float* ig = partials + 7 * 64;

  WDesc wd;
  int cum = 0;
  size_t qoff[7]; size_t qc = 0;
  for (int l = 0; l < 7; ++l) {
    wd.W[l] = Wptr[l];
    int nv = Ns[l] * Ks[l] / 4;
    wd.nvec[l] = nv;
    wd.vcum[l] = cum;
    cum += nv;
    qoff[l] = qc;
    qc += (size_t)Ns[l] * Ks[l];
  }
  wd.vcum[7] = cum;

  const int qblks = (cum + 255) / 256;
  absmean_partial<<<dim3(64, 7), 256, 0, stream>>>(wd, partials);
  absmean_final<<<7, 64, 0, stream>>>(wd, partials, ig);
  prep_kernel<<<qblks + 8192, 256, 0, stream>>>(wd, ig, qw, z, att, bufA, qblks);

  ushort* inb = bufA; ushort* outb = bufB;
  // L0: 8192x1024, K=2048 -> pipe3 <BN=128>, grid (8,32)=256
  gemm_pipe3<128, false><<<dim3(Ns[0] / 128, M / 256), dim3(512), 0, stream>>>(
      inb, qw + qoff[0], bptr[0], outb, M, Ns[0], Ks[0]);
  { ushort* tmp = inb; inb = outb; outb = tmp; }
  // L1: 8192x512, K=1024 -> pipe3 <BN=64>, grid (8,32)=256
  gemm_pipe3<64, false><<<dim3(Ns[1] / 64, M / 256), dim3(512), 0, stream>>>(
      inb, qw + qoff[1], bptr[1], outb, M, Ns[1], Ks[1]);
  { ushort* tmp = inb; inb = outb; outb = tmp; }
  // L2: 8192x256, K=512 -> 2-phase <64,64>
  gemm_bt_bias_gelu<64, 64, false><<<dim3(Ns[2] / 64, M / 64), 256, 0, stream>>>(
      inb, qw + qoff[2], bptr[2], outb, M, Ns[2], Ks[2]);
  { ushort* tmp = inb; inb = outb; outb = tmp; }
  // L3: 8192x256, K=256 -> 2-phase <64,64>
  gemm_bt_bias_gelu<64, 64, false><<<dim3(Ns[3] / 64, M / 64), 256, 0, stream>>>(
      inb, qw + qoff[3], bptr[3], outb, M, Ns[3], Ks[3]);
  { ushort* tmp = inb; inb = outb; outb = tmp; }
  // L4: 8192x512, K=256 -> pipe3 <BN=64>, grid (8,32)=256
  gemm_pipe3<64, false><<<dim3(Ns[4] / 64, M / 256), dim3(512), 0, stream>>>(
      inb, qw + qoff[4], bptr[4], outb, M, Ns[4], Ks[4]);
  { ushort* tmp = inb; inb = outb; outb = tmp; }
  // L5: 8192x1024, K=512 -> pipe3 <BN=128>, grid (8,32)
  gemm_pipe3<128, false><<<dim3(Ns[5] / 128, M / 256), dim3(512), 0, stream>>>(
      inb, qw + qoff[5], bptr[5], outb, M, Ns[5], Ks[5]);
  { ushort* tmp = inb; inb = outb; outb = tmp; }
  // L6: 8192x2048, K=1024 -> gemm_8p2 (deep-pipelined 8-phase, corrected
  // m201 mechanism: full-reg fragments, early buffer death, one VMW(4)
  // per tile with 1.5-tile slack). grid (8,32)=256, fp32 out.
  gemm_8p2<true><<<dim3(Ns[6] / 256, M / 256), dim3(512), 0, stream>>>(
      inb, qw + qoff[6], bptr[6], d_out, M, Ns[6], Ks[6]);
}